// Round 4
// baseline (312.322 us; speedup 1.0000x reference)
//
#include <hip/hip_runtime.h>

// Problem constants (fixed by the reference)
#define N2 2048
#define NNZ 32768
#define LK 22          // FROZEN: absmax 0.0234 of 0.037 threshold (3 of ~4.7 bf16 ulps)
#define NBL 128        // lanczos grid blocks: 128 x 512 thr; 147KB LDS -> 1 block/CU
#define BINCAP 64      // slots per row bin (Poisson(16) tail ~1e-15)

typedef __attribute__((ext_vector_type(8))) _Float16 half8;
typedef __attribute__((ext_vector_type(4))) float f32x4;

#define AGENT __HIP_MEMORY_SCOPE_AGENT
#define AS1C(p) ((const __attribute__((address_space(1))) unsigned int*)(p))
#define AS3(p)  ((__attribute__((address_space(3))) unsigned int*)(p))

__device__ __forceinline__ unsigned short f2h(float f) {
  _Float16 h = (_Float16)f;                   // fp16 RNE; |W| < ~5.5, in range
  return *(unsigned short*)&h;
}

// ---- 1. W (fp32) -> fp16  (+ zero cnt for the binning pass) ----
__global__ __launch_bounds__(256) void convert_kernel(const float* __restrict__ W,
                                                      unsigned short* __restrict__ Hf,
                                                      unsigned* __restrict__ cnt) {
  if (blockIdx.x < 8) cnt[blockIdx.x * 256 + threadIdx.x] = 0;
  int i4 = blockIdx.x * 256 + threadIdx.x;          // grid 4096 -> 1048576 float4s
  float4 w = ((const float4*)W)[i4];
  ushort4 h;
  h.x = f2h(w.x); h.y = f2h(w.y); h.z = f2h(w.z); h.w = f2h(w.w);
  ((ushort4*)Hf)[i4] = h;
}

// ---- 2. A = Hf*Hf^T/N + I  (single fp16 pass; exactly symmetric by construction:
//         (W+E)(W+E)^T — no symmetrization pass needed; eig shift <= 2|W||E|/N ~ 0.0024)
//         64x128 tile, 512 blocks = 2/CU at N=2048; epilogue applies /N + I ----
__global__ __launch_bounds__(256) void gemm_f16_kernel(const unsigned short* __restrict__ Hf,
                                                       float* __restrict__ A) {
  __shared__ unsigned short Xs[64 * 32];
  __shared__ unsigned short Ys[128 * 32];
  const int tid = threadIdx.x;
  const int wave = tid >> 6, lane = tid & 63;
  const int bi = blockIdx.x >> 4, bj = blockIdx.x & 15;   // 32 x 16 tiles
  const int row0 = bi * 64, col0 = bj * 128;
  const int m0 = (wave & 1) * 32, n0 = (wave >> 1) * 64;
  f32x4 acc[2][4];
#pragma unroll
  for (int a = 0; a < 2; ++a)
#pragma unroll
    for (int b = 0; b < 4; ++b) acc[a][b] = (f32x4){0.f, 0.f, 0.f, 0.f};
  const int mrow = lane & 15, kseg = (lane >> 4) * 8;
  // async staging (wave-uniform base + lane*16B, contiguous):
  const int srowX = wave * 16 + (lane >> 2);          // Xs: 64 rows, 1 issue/wave
  const int srowY = wave * 32 + (lane >> 2);          // Ys: 128 rows, 2 issues/wave
  const int scol = (lane & 3) * 8;

  for (int k0 = 0; k0 < 2048; k0 += 32) {
    __syncthreads();
    __builtin_amdgcn_global_load_lds(
        AS1C(Hf + (size_t)(row0 + srowX) * 2048 + k0 + scol),
        AS3(Xs + (wave * 16) * 32), 16, 0, 0);
#pragma unroll
    for (int q = 0; q < 2; ++q) {
      __builtin_amdgcn_global_load_lds(
          AS1C(Hf + (size_t)(col0 + srowY + q * 16) * 2048 + k0 + scol),
          AS3(Ys + (wave * 32 + q * 16) * 32), 16, 0, 0);
    }
    __syncthreads();
    half8 af[2], bf[4];
#pragma unroll
    for (int t = 0; t < 2; ++t)
      af[t] = *(const half8*)(Xs + (m0 + t * 16 + mrow) * 32 + kseg);
#pragma unroll
    for (int t = 0; t < 4; ++t)
      bf[t] = *(const half8*)(Ys + (n0 + t * 16 + mrow) * 32 + kseg);
#pragma unroll
    for (int mt = 0; mt < 2; ++mt)
#pragma unroll
      for (int nt = 0; nt < 4; ++nt)
        acc[mt][nt] = __builtin_amdgcn_mfma_f32_16x16x32_f16(af[mt], bf[nt], acc[mt][nt], 0, 0, 0);
  }
  // C/D layout: col = lane&15, row = (lane>>4)*4 + reg   [m89-verified, dtype-indep]
  const int crow = (lane >> 4) * 4, ccol = lane & 15;
  const float invn = 1.0f / 2048.0f;
#pragma unroll
  for (int mt = 0; mt < 2; ++mt)
#pragma unroll
    for (int nt = 0; nt < 4; ++nt) {
      const int gi0 = row0 + m0 + mt * 16 + crow;
      const int gj = col0 + n0 + nt * 16 + ccol;
      size_t base = (size_t)gi0 * 2048 + gj;
#pragma unroll
      for (int r = 0; r < 4; ++r)
        A[base + (size_t)r * 2048] = acc[mt][nt][r] * invn + ((gi0 + r == gj) ? 1.0f : 0.0f);
    }
}

// ---- 4. fill fixed-stride bins: slot = atomic alloc in cnt[r] (no count/scan) ----
__global__ __launch_bounds__(256) void fill_kernel(const float* __restrict__ pred,
                                                   const float* __restrict__ scal,
                                                   const int* __restrict__ rows,
                                                   const int* __restrict__ cols,
                                                   unsigned* __restrict__ cnt,
                                                   int* __restrict__ bcol,
                                                   float* __restrict__ bval) {
  int k = blockIdx.x * 256 + threadIdx.x;
  int r = rows[k];
  unsigned pos = atomicAdd(&cnt[r], 1u);
  if (pos < BINCAP) {                       // Poisson(16) tail guard, ~never taken
    bcol[r * BINCAP + pos] = cols[k];
    bval[r * BINCAP + pos] = pred[k] * scal[k];
  }
}

// ---- 4d. F[r,:] = sum_e val_e * A[col_e,:]  (float4, block r owns row r) ----
__global__ __launch_bounds__(256) void gatherF_kernel(const unsigned* __restrict__ cnt,
                                                      const int* __restrict__ bcol,
                                                      const float* __restrict__ bval,
                                                      const float* __restrict__ A,
                                                      float* __restrict__ F) {
  const int r = blockIdx.x, tid = threadIdx.x;
  float4 a0 = {0.f, 0.f, 0.f, 0.f}, a1 = {0.f, 0.f, 0.f, 0.f};
  const unsigned ne = min(cnt[r], (unsigned)BINCAP);
  for (unsigned e = 0; e < ne; ++e) {
    const float v = bval[r * BINCAP + e];
    const float4* Ar = (const float4*)(A + (size_t)bcol[r * BINCAP + e] * 2048);
    float4 x0 = Ar[tid], x1 = Ar[tid + 256];
    a0.x += v * x0.x; a0.y += v * x0.y; a0.z += v * x0.z; a0.w += v * x0.w;
    a1.x += v * x1.x; a1.y += v * x1.y; a1.z += v * x1.z; a1.w += v * x1.w;
  }
  float4* Fr = (float4*)(F + (size_t)r * 2048);
  Fr[tid] = a0;
  Fr[tid + 256] = a1;
}

// ---- 4e. M[r,:] += sum_e val_e * Ft[col_e,:]  (float4) ----
__global__ __launch_bounds__(256) void gatherM_kernel(const unsigned* __restrict__ cnt,
                                                      const int* __restrict__ bcol,
                                                      const float* __restrict__ bval,
                                                      const float* __restrict__ Ft,
                                                      float* __restrict__ M) {
  const int r = blockIdx.x, tid = threadIdx.x;
  float4 a0 = {0.f, 0.f, 0.f, 0.f}, a1 = {0.f, 0.f, 0.f, 0.f};
  const unsigned ne = min(cnt[r], (unsigned)BINCAP);
  for (unsigned e = 0; e < ne; ++e) {
    const float v = bval[r * BINCAP + e];
    const float4* Fr = (const float4*)(Ft + (size_t)bcol[r * BINCAP + e] * 2048);
    float4 x0 = Fr[tid], x1 = Fr[tid + 256];
    a0.x += v * x0.x; a0.y += v * x0.y; a0.z += v * x0.z; a0.w += v * x0.w;
    a1.x += v * x1.x; a1.y += v * x1.y; a1.z += v * x1.z; a1.w += v * x1.w;
  }
  float4* Mr = (float4*)(M + (size_t)r * 2048);
  float4 m0 = Mr[tid], m1 = Mr[tid + 256];
  m0.x += a0.x; m0.y += a0.y; m0.z += a0.z; m0.w += a0.w;
  m1.x += a1.x; m1.y += a1.y; m1.z += a1.z; m1.w += a1.w;
  Mr[tid] = m0;
  Mr[tid + 256] = m1;
}

// ---- 5. M += F + F^T;  Ft = F^T ----
__global__ __launch_bounds__(256) void addsym_kernel(const float* __restrict__ F,
                                                     float* __restrict__ M,
                                                     float* __restrict__ Ft) {
  __shared__ float T2[32][33];
  const int bi = blockIdx.x, bj = blockIdx.y;
  const int c = threadIdx.x & 31, r0 = threadIdx.x >> 5;
#pragma unroll
  for (int it = 0; it < 4; ++it) {
    int r = r0 + it * 8;
    T2[r][c] = F[(size_t)(bj * 32 + r) * 2048 + bi * 32 + c];
  }
  __syncthreads();
#pragma unroll
  for (int it = 0; it < 4; ++it) {
    int r = r0 + it * 8;
    size_t idx = (size_t)(bi * 32 + r) * 2048 + bj * 32 + c;
    float ft = T2[c][r];
    M[idx] += F[idx] + ft;
    Ft[idx] = ft;
  }
}

// ---- deterministic block-wide sum over 8 waves: bitwise-identical per block ----
__device__ __forceinline__ float block_sum8(float v, float* red) {
#pragma unroll
  for (int off = 32; off; off >>= 1) v += __shfl_down(v, off);
  if ((threadIdx.x & 63) == 0) red[threadIdx.x >> 6] = v;
  __syncthreads();
  float r = ((red[0] + red[1]) + (red[2] + red[3])) +
            ((red[4] + red[5]) + (red[6] + red[7]));
  __syncthreads();
  return r;
}

// ---- 6. Lanczos: single-phase epoch protocol, 128 x 512 decomposition ----
// LAUNCHED AS A PLAIN KERNEL (R14). Co-residency by construction: 147 KB LDS
// -> HW fits exactly 1 block/CU, so 128 blocks land on 128 distinct CUs, all
// resident at t=0; spin protocol cannot deadlock.
// RULE 1 (R1/R6): every cross-block datum moves via agent-scope atomic loads
// AND stores. Each Z entry is a 64-bit word {epoch j | float bits}; one polled
// 8B agent load is both barrier and data.
// RULE 2 (R1/R6/R8): beta^2 = ||z - alpha v||^2 DIRECT form only.
// RULE 3 (R16): no fixed-address staging reuse with plain "cache-bypass" loads.
// RULE 4 (R17): exactly ONE publish->consume phase per iteration (two-phase
// flag barrier cost +3.7 us/iter).
// RULE 5 (R19, this round): exchange cost scales with #polling-agents —
// per poll round the grid issues (blocks x 256) uncacheable line-requests at
// the coherence point (~20 lines/cy at 256 blocks; backoff win R18 confirmed
// request-rate-bound). 128 x 512 halves the request flood and the arrival
// count at identical total Mv work (1024 waves either way). Each block owns
// 16 M rows staged once to LDS (128 KB; 82 KB static LDS already proven OK).
// Ping-pong clobber safety is block-count-independent: a block writes Z_{j+1}
// only after consuming ALL of Z_j, which proves grid-wide consumption of
// Z_{j-1}. Poison epochs fail the equality check; stale epochs from a prior
// replay carry bit-identical payloads (fully deterministic pipeline) => safe.
__global__ __launch_bounds__(512) void lanczos_kernel(const float* __restrict__ M,
                                                      unsigned long long* __restrict__ Z0,
                                                      unsigned long long* __restrict__ Z1,
                                                      float* __restrict__ out) {
  const int tid = threadIdx.x, b = blockIdx.x;
  const int wave = tid >> 6, lane = tid & 63;
  __shared__ __align__(16) float Mlds[16 * 2048];  // 128 KB: this block's 16 rows
  __shared__ __align__(16) float VA[2048];
  __shared__ __align__(16) float VB[2048];
  __shared__ float red[8];
  __shared__ float al[LK + 2], b2[LK + 2];
  __shared__ float bnds[2], res[2];

  // stage M rows first: 8 waves x 16 issues x 1 KB, contiguous 128 KB; the
  // global->LDS latency overlaps the v1 hash init; first __syncthreads drains.
  const float* Mblk = M + (size_t)b * 16 * 2048;
#pragma unroll
  for (int q = 0; q < 16; ++q)
    __builtin_amdgcn_global_load_lds(AS1C(Mblk + wave * 4096 + q * 256 + lane * 4),
                                     AS3(Mlds + wave * 4096 + q * 256), 16, 0, 0);

  // block-redundant init: v1 = hash / ||hash||  (identical in every block), v0 = 0
  float pv[4];
  float part = 0.f;
#pragma unroll
  for (int t = 0; t < 4; ++t) {
    int i = t * 512 + tid;
    unsigned u = (unsigned)i * 2654435761u;
    u ^= u >> 16; u *= 2246822519u; u ^= u >> 13;
    float rv = (float)(u >> 8) * (2.f / 16777216.f) - 1.f;
    pv[t] = rv;
    part += rv * rv;
  }
  float nrm = block_sum8(part, red);
  float innm = rsqrtf(nrm);
#pragma unroll
  for (int t = 0; t < 4; ++t) {
    int i = t * 512 + tid;
    VA[i] = pv[t] * innm;
    VB[i] = 0.f;
  }
  __syncthreads();

  float* Vcur = VA;
  float* Vprev = VB;
  float beta_prev = 0.f;

  for (int j = 1; j <= LK; ++j) {
    unsigned long long* Z = (j & 1) ? Z0 : Z1;
    // --- this block's 16 rows of z = M v_j - beta_{j-1} v_{j-1} (all-LDS Mv);
    //     each wave publishes its 2 rows as soon as they're done (early pub) ---
#pragma unroll
    for (int rr = 0; rr < 2; ++rr) {
      const int r = b * 16 + wave * 2 + rr;
      const float4* Mr = (const float4*)(Mlds + (wave * 2 + rr) * 2048);
      float s = 0.f;
#pragma unroll
      for (int t = 0; t < 8; ++t) {
        int idx = t * 64 + lane;
        float4 m4 = Mr[idx];
        float4 v4 = ((const float4*)Vcur)[idx];
        s += m4.x * v4.x + m4.y * v4.y + m4.z * v4.z + m4.w * v4.w;
      }
#pragma unroll
      for (int off = 32; off; off >>= 1) s += __shfl_down(s, off);
      if (lane == 0) {
        float zv = s - beta_prev * Vprev[r];
        unsigned long long pk = ((unsigned long long)(unsigned)j << 32) |
                                (unsigned long long)(unsigned)__float_as_uint(zv);
        __hip_atomic_store(&Z[r], pk, __ATOMIC_RELAXED, AGENT);
      }
    }

    // hoist own v-slice reads (LDS) ahead of the poll — free overlap
    float va[4];
#pragma unroll
    for (int t = 0; t < 4; ++t) va[t] = Vcur[t * 512 + tid];

    // --- poll own 4 Z words until their epoch == j (single-phase, fused
    //     data+flag); batched issue (one waitcnt) + capped-exp backoff ---
    unsigned long long w4[4];
    int rounds = 0;
    for (;;) {
      bool ok = true;
#pragma unroll
      for (int t = 0; t < 4; ++t) {
        w4[t] = __hip_atomic_load(&Z[t * 512 + tid], __ATOMIC_RELAXED, AGENT);
        ok &= ((unsigned)(w4[t] >> 32) == (unsigned)j);
      }
      if (ok) break;
      // capped-exponential backoff; s_sleep wants a literal immediate
      if (rounds == 1)      __builtin_amdgcn_s_sleep(1);   //  64 clk
      else if (rounds == 2) __builtin_amdgcn_s_sleep(2);   // 128 clk
      else if (rounds >= 3) __builtin_amdgcn_s_sleep(8);   // 512 clk
      ++rounds;
    }
    // --- redundant deterministic scalars, DIRECT beta form (Rule 2) ---
    float za[4];
    float pa = 0.f;
#pragma unroll
    for (int t = 0; t < 4; ++t) {
      za[t] = __uint_as_float((unsigned)w4[t]);
      pa += za[t] * va[t];
    }
    float alpha = block_sum8(pa, red);
    float pb = 0.f;
#pragma unroll
    for (int t = 0; t < 4; ++t) {
      float rsd = za[t] - alpha * va[t];
      pb += rsd * rsd;
    }
    float beta2 = block_sum8(pb, red);
    float beta = sqrtf(fmaxf(beta2, 1e-30f));
    float invb = 1.f / beta;
    if (tid == 0) { al[j] = alpha; b2[j] = beta2; }
    // rotate: overwrite Vprev storage (v_{j-1} dead) with v_{j+1}
#pragma unroll
    for (int t = 0; t < 4; ++t) {
      int i = t * 512 + tid;
      Vprev[i] = (za[t] - alpha * va[t]) * invb;
    }
    float* tmp = Vprev; Vprev = Vcur; Vcur = tmp;
    beta_prev = beta;
    __syncthreads();
  }

  // ---- extreme eigenvalues of T via Sturm bisection (block 0) ----
  if (b == 0) {
    if (tid == 0) {                                  // Gershgorin bounds on T
      float lo = 1e30f, hi = -1e30f;
      for (int i = 1; i <= LK; ++i) {
        float bl = (i > 1) ? sqrtf(b2[i - 1]) : 0.f;
        float br = (i < LK) ? sqrtf(b2[i]) : 0.f;
        lo = fminf(lo, al[i] - bl - br);
        hi = fmaxf(hi, al[i] + bl + br);
      }
      bnds[0] = lo; bnds[1] = hi;
    }
    __syncthreads();
    if (wave < 2) {                 // wave 0 -> lambda_min, wave 1 -> lambda_max
      const int tcount = (wave == 0) ? 1 : LK;
      float lo = bnds[0], hi = bnds[1];
      for (int round = 0; round < 4; ++round) {
        float x = lo + (hi - lo) * (float)(lane + 1) * (1.f / 65.f);
        int cnt = 0;                                 // #eigs of T below x
        float d = al[1] - x;
        if (fabsf(d) < 1e-25f) d = -1e-25f;
        if (d < 0.f) cnt++;
        for (int i = 2; i <= LK; ++i) {
          d = (al[i] - x) - b2[i - 1] / d;
          if (fabsf(d) < 1e-25f) d = -1e-25f;
          if (d < 0.f) cnt++;
        }
        bool ab = (cnt >= tcount);                   // x is above the target eig
        float cand_hi = ab ? x : hi;
        float cand_lo = ab ? lo : x;
#pragma unroll
        for (int off = 32; off; off >>= 1) {
          cand_hi = fminf(cand_hi, __shfl_down(cand_hi, off));
          cand_lo = fmaxf(cand_lo, __shfl_down(cand_lo, off));
        }
        cand_hi = __shfl(cand_hi, 0);
        cand_lo = __shfl(cand_lo, 0);
        hi = cand_hi;
        lo = fminf(cand_lo, hi);
      }
      if (lane == 0) res[wave] = 0.5f * (lo + hi);
    }
    __syncthreads();
    if (tid == 0) {
      float lmin = fmaxf(res[0], 1e-12f);
      float lmax = fmaxf(res[1], 1e-12f);
      out[0] = logf(lmax) - logf(lmin);
    }
  }
}

extern "C" void kernel_launch(void* const* d_in, const int* in_sizes, int n_in,
                              void* d_out, int out_size, void* d_ws, size_t ws_size,
                              hipStream_t stream) {
  const float* pred = (const float*)d_in[0];
  const float* scal = (const float*)d_in[1];
  const float* W    = (const float*)d_in[2];
  const int*   rows = (const int*)d_in[3];
  const int*   cols = (const int*)d_in[4];
  float* out = (float*)d_out;

  // workspace layout (peak ~49.1 MB):
  //  [0,16MB)  : Hf fp16 (8MB) during GEMM, then Ft (16MB)
  //  [16,32MB) : F
  //  [32,48MB) : A (written directly by GEMM), updated in place into M
  //  [48MB,..) : cnt, fixed-stride bins, epoch-tagged Z ping-pong
  char* ws = (char*)d_ws;
  const size_t MB = 1024 * 1024;
  unsigned short* Hf = (unsigned short*)(ws);
  float* F  = (float*)(ws + 16 * MB);
  float* A  = (float*)(ws + 32 * MB);
  float* Ft = (float*)(ws);             // reuses Hf (dead after gemm)
  char* ctrl = ws + 48 * MB;
  unsigned* cnt  = (unsigned*)(ctrl);                    //  8 KB (zeroed by convert)
  int*      bcol = (int*)(ctrl + 8192);                  //  512 KB (2048 x 64)
  float*    bval = (float*)(ctrl + 8192 + 524288);       //  512 KB
  unsigned long long* Z0 = (unsigned long long*)(ctrl + 8192 + 1048576);         // 16 KB
  unsigned long long* Z1 = (unsigned long long*)(ctrl + 8192 + 1048576 + 16384); // 16 KB

  convert_kernel<<<4096, 256, 0, stream>>>(W, Hf, cnt);
  gemm_f16_kernel<<<512, 256, 0, stream>>>(Hf, A);       // A = W W^T/N + I directly

  fill_kernel<<<NNZ / 256, 256, 0, stream>>>(pred, scal, rows, cols, cnt, bcol, bval);

  gatherF_kernel<<<2048, 256, 0, stream>>>(cnt, bcol, bval, A, F);   // F = S*A
  addsym_kernel<<<dim3(64, 64), 256, 0, stream>>>(F, A, Ft);         // M = A+F+F^T; Ft=F^T
  gatherM_kernel<<<2048, 256, 0, stream>>>(cnt, bcol, bval, Ft, A);  // M += S*F^T

  // plain launch — 128 blocks x 512 threads, 147KB LDS => 1 block/CU, all resident
  lanczos_kernel<<<NBL, 512, 0, stream>>>(A, Z0, Z1, out);
}

// Round 5
// 311.056 us; speedup vs baseline: 1.0041x; 1.0041x over previous
//
#include <hip/hip_runtime.h>

// Problem constants (fixed by the reference)
#define N2 2048
#define NNZ 32768
#define LK 22          // FROZEN: absmax 0.0234 of 0.037 threshold (3 of ~4.7 bf16 ulps)
#define NBL 128        // lanczos grid blocks: 128 x 512 thr; 147KB LDS -> 1 block/CU
#define BINCAP 64      // slots per row bin (Poisson(16) tail ~1e-15)

typedef __attribute__((ext_vector_type(8))) _Float16 half8;
typedef __attribute__((ext_vector_type(4))) float f32x4;

#define AGENT __HIP_MEMORY_SCOPE_AGENT
#define AS1C(p) ((const __attribute__((address_space(1))) unsigned int*)(p))
#define AS3(p)  ((__attribute__((address_space(3))) unsigned int*)(p))

__device__ __forceinline__ unsigned short f2h(float f) {
  _Float16 h = (_Float16)f;                   // fp16 RNE; |W| < ~5.5, in range
  return *(unsigned short*)&h;
}

// ---- 1. W (fp32) -> fp16  (+ zero cnt for the binning pass) ----
__global__ __launch_bounds__(256) void convert_kernel(const float* __restrict__ W,
                                                      unsigned short* __restrict__ Hf,
                                                      unsigned* __restrict__ cnt) {
  if (blockIdx.x < 8) cnt[blockIdx.x * 256 + threadIdx.x] = 0;
  int i4 = blockIdx.x * 256 + threadIdx.x;          // grid 4096 -> 1048576 float4s
  float4 w = ((const float4*)W)[i4];
  ushort4 h;
  h.x = f2h(w.x); h.y = f2h(w.y); h.z = f2h(w.z); h.w = f2h(w.w);
  ((ushort4*)Hf)[i4] = h;
}

// ---- 2. A = Hf*Hf^T/N + I   — in-block split-K edition (R20) ----
// 512 tiles of 64x128; 512 threads/block: waves 0-3 accumulate k in [0,1024),
// waves 4-7 k in [1024,2048). 16 waves/CU (2 blocks x 8 waves; LDS 57.8KB ->
// 2 blocks/CU) doubles latency-hiding vs the old 4-wave block; barrier count
// halves. Halves combine via padded LDS (stride 132 -> 2-way banks, free) and
// a single plain store — no atomics, deterministic fixed-order (low + high).
// NOTE: two k-chains + one fp32 add is not bitwise the old single chain; the
// eig shift is ~1e-6 relative — absmax budget unaffected (fp16 dominates).
// Fused fill (blocks 0-63): scatter the 32768 sparse entries into bins before
// the tile loop; cnt was zeroed by convert (prior kernel) so no race; bins are
// read only by gatherF (next kernel). Saves one launch + gap.
__global__ __launch_bounds__(512) void gemm_f16_kernel(const unsigned short* __restrict__ Hf,
                                                       float* __restrict__ A,
                                                       const float* __restrict__ pred,
                                                       const float* __restrict__ scal,
                                                       const int* __restrict__ rows,
                                                       const int* __restrict__ cols,
                                                       unsigned* __restrict__ cnt,
                                                       int* __restrict__ bcol,
                                                       float* __restrict__ bval) {
  const int tid = threadIdx.x;
  // ---- fused fill: 64 blocks x 512 threads cover NNZ=32768 ----
  if (blockIdx.x < 64) {
    int k = blockIdx.x * 512 + tid;
    int r = rows[k];
    unsigned pos = atomicAdd(&cnt[r], 1u);
    if (pos < BINCAP) {                     // Poisson(16) tail guard, ~never taken
      bcol[r * BINCAP + pos] = cols[k];
      bval[r * BINCAP + pos] = pred[k] * scal[k];
    }
  }

  __shared__ unsigned short Xs[2][64 * 32];
  __shared__ unsigned short Ys[2][128 * 32];
  __shared__ float Cred[64 * 132];          // pad 128->132: 2-way banks (free)
  const int w = tid >> 6, lane = tid & 63;
  const int half = w >> 2, wq = w & 3;      // k-half, role within half
  const int bi = blockIdx.x >> 4, bj = blockIdx.x & 15;   // 32 x 16 tiles
  const int row0 = bi * 64, col0 = bj * 128;
  const int m0 = (wq & 1) * 32, n0 = (wq >> 1) * 64;
  f32x4 acc[2][4];
#pragma unroll
  for (int a = 0; a < 2; ++a)
#pragma unroll
    for (int b = 0; b < 4; ++b) acc[a][b] = (f32x4){0.f, 0.f, 0.f, 0.f};
  const int mrow = lane & 15, kseg = (lane >> 4) * 8;
  // async staging (wave-uniform base + lane*16B, contiguous):
  const int srowX = wq * 16 + (lane >> 2);          // Xs: 16 rows/wave
  const int srowY = wq * 32 + (lane >> 2);          // Ys: 32 rows/wave (2 issues)
  const int scol = (lane & 3) * 8;
  const int kbase = half * 1024;

  for (int k0 = 0; k0 < 1024; k0 += 32) {
    __syncthreads();
    __builtin_amdgcn_global_load_lds(
        AS1C(Hf + (size_t)(row0 + srowX) * 2048 + kbase + k0 + scol),
        AS3(Xs[half] + (wq * 16) * 32), 16, 0, 0);
#pragma unroll
    for (int q = 0; q < 2; ++q) {
      __builtin_amdgcn_global_load_lds(
          AS1C(Hf + (size_t)(col0 + srowY + q * 16) * 2048 + kbase + k0 + scol),
          AS3(Ys[half] + (wq * 32 + q * 16) * 32), 16, 0, 0);
    }
    __syncthreads();
    half8 af[2], bf[4];
#pragma unroll
    for (int t = 0; t < 2; ++t)
      af[t] = *(const half8*)(Xs[half] + (m0 + t * 16 + mrow) * 32 + kseg);
#pragma unroll
    for (int t = 0; t < 4; ++t)
      bf[t] = *(const half8*)(Ys[half] + (n0 + t * 16 + mrow) * 32 + kseg);
#pragma unroll
    for (int mt = 0; mt < 2; ++mt)
#pragma unroll
      for (int nt = 0; nt < 4; ++nt)
        acc[mt][nt] = __builtin_amdgcn_mfma_f32_16x16x32_f16(af[mt], bf[nt], acc[mt][nt], 0, 0, 0);
  }
  // ---- combine halves: high -> LDS, low adds and stores ----
  // C/D layout: col = lane&15, row = (lane>>4)*4 + reg   [m89-verified]
  const int crow = (lane >> 4) * 4, ccol = lane & 15;
  __syncthreads();
  if (half == 1) {
#pragma unroll
    for (int mt = 0; mt < 2; ++mt)
#pragma unroll
      for (int nt = 0; nt < 4; ++nt)
#pragma unroll
        for (int r = 0; r < 4; ++r)
          Cred[(m0 + mt * 16 + crow + r) * 132 + n0 + nt * 16 + ccol] = acc[mt][nt][r];
  }
  __syncthreads();
  if (half == 0) {
    const float invn = 1.0f / 2048.0f;
#pragma unroll
    for (int mt = 0; mt < 2; ++mt)
#pragma unroll
      for (int nt = 0; nt < 4; ++nt) {
        const int gi0 = row0 + m0 + mt * 16 + crow;
        const int gj = col0 + n0 + nt * 16 + ccol;
        size_t base = (size_t)gi0 * 2048 + gj;
#pragma unroll
        for (int r = 0; r < 4; ++r) {
          float v = acc[mt][nt][r] +
                    Cred[(m0 + mt * 16 + crow + r) * 132 + n0 + nt * 16 + ccol];
          A[base + (size_t)r * 2048] = v * invn + ((gi0 + r == gj) ? 1.0f : 0.0f);
        }
      }
  }
}

// ---- 4d. F[r,:] = sum_e val_e * A[col_e,:]  (float4, block r owns row r) ----
__global__ __launch_bounds__(256) void gatherF_kernel(const unsigned* __restrict__ cnt,
                                                      const int* __restrict__ bcol,
                                                      const float* __restrict__ bval,
                                                      const float* __restrict__ A,
                                                      float* __restrict__ F) {
  const int r = blockIdx.x, tid = threadIdx.x;
  float4 a0 = {0.f, 0.f, 0.f, 0.f}, a1 = {0.f, 0.f, 0.f, 0.f};
  const unsigned ne = min(cnt[r], (unsigned)BINCAP);
  for (unsigned e = 0; e < ne; ++e) {
    const float v = bval[r * BINCAP + e];
    const float4* Ar = (const float4*)(A + (size_t)bcol[r * BINCAP + e] * 2048);
    float4 x0 = Ar[tid], x1 = Ar[tid + 256];
    a0.x += v * x0.x; a0.y += v * x0.y; a0.z += v * x0.z; a0.w += v * x0.w;
    a1.x += v * x1.x; a1.y += v * x1.y; a1.z += v * x1.z; a1.w += v * x1.w;
  }
  float4* Fr = (float4*)(F + (size_t)r * 2048);
  Fr[tid] = a0;
  Fr[tid + 256] = a1;
}

// ---- 4e. M[r,:] += sum_e val_e * Ft[col_e,:]  (float4) ----
__global__ __launch_bounds__(256) void gatherM_kernel(const unsigned* __restrict__ cnt,
                                                      const int* __restrict__ bcol,
                                                      const float* __restrict__ bval,
                                                      const float* __restrict__ Ft,
                                                      float* __restrict__ M) {
  const int r = blockIdx.x, tid = threadIdx.x;
  float4 a0 = {0.f, 0.f, 0.f, 0.f}, a1 = {0.f, 0.f, 0.f, 0.f};
  const unsigned ne = min(cnt[r], (unsigned)BINCAP);
  for (unsigned e = 0; e < ne; ++e) {
    const float v = bval[r * BINCAP + e];
    const float4* Fr = (const float4*)(Ft + (size_t)bcol[r * BINCAP + e] * 2048);
    float4 x0 = Fr[tid], x1 = Fr[tid + 256];
    a0.x += v * x0.x; a0.y += v * x0.y; a0.z += v * x0.z; a0.w += v * x0.w;
    a1.x += v * x1.x; a1.y += v * x1.y; a1.z += v * x1.z; a1.w += v * x1.w;
  }
  float4* Mr = (float4*)(M + (size_t)r * 2048);
  float4 m0 = Mr[tid], m1 = Mr[tid + 256];
  m0.x += a0.x; m0.y += a0.y; m0.z += a0.z; m0.w += a0.w;
  m1.x += a1.x; m1.y += a1.y; m1.z += a1.z; m1.w += a1.w;
  Mr[tid] = m0;
  Mr[tid + 256] = m1;
}

// ---- 5. M += F + F^T;  Ft = F^T ----
__global__ __launch_bounds__(256) void addsym_kernel(const float* __restrict__ F,
                                                     float* __restrict__ M,
                                                     float* __restrict__ Ft) {
  __shared__ float T2[32][33];
  const int bi = blockIdx.x, bj = blockIdx.y;
  const int c = threadIdx.x & 31, r0 = threadIdx.x >> 5;
#pragma unroll
  for (int it = 0; it < 4; ++it) {
    int r = r0 + it * 8;
    T2[r][c] = F[(size_t)(bj * 32 + r) * 2048 + bi * 32 + c];
  }
  __syncthreads();
#pragma unroll
  for (int it = 0; it < 4; ++it) {
    int r = r0 + it * 8;
    size_t idx = (size_t)(bi * 32 + r) * 2048 + bj * 32 + c;
    float ft = T2[c][r];
    M[idx] += F[idx] + ft;
    Ft[idx] = ft;
  }
}

// ---- deterministic block-wide sum over 8 waves: bitwise-identical per block ----
__device__ __forceinline__ float block_sum8(float v, float* red) {
#pragma unroll
  for (int off = 32; off; off >>= 1) v += __shfl_down(v, off);
  if ((threadIdx.x & 63) == 0) red[threadIdx.x >> 6] = v;
  __syncthreads();
  float r = ((red[0] + red[1]) + (red[2] + red[3])) +
            ((red[4] + red[5]) + (red[6] + red[7]));
  __syncthreads();
  return r;
}

// ---- 6. Lanczos: single-phase epoch protocol, 128 x 512 — FROZEN (R20) ----
// R20 conclusion: ~4.2 us/iter exchange is the store->remote-observability
// floor of an agent-scope publish under polling on this fabric — robust to
// protocol shape (R0/R1/R3), traffic volume (backoff R3), and agent count
// (R4: 128x512 == 256x256). Do not tune further without a new mechanism.
// RULE 1 (R1/R6): cross-block data via agent-scope atomics only.
// RULE 2 (R1/R6/R8): beta^2 = ||z - alpha v||^2 DIRECT form only.
// RULE 3 (R16): no fixed-address staging reuse with plain cached loads.
// RULE 4 (R17): exactly ONE publish->consume phase per iteration.
// RULE 5 (R19/R20): exchange cost is per-phase visibility latency, NOT
// request-rate at these scales.
__global__ __launch_bounds__(512) void lanczos_kernel(const float* __restrict__ M,
                                                      unsigned long long* __restrict__ Z0,
                                                      unsigned long long* __restrict__ Z1,
                                                      float* __restrict__ out) {
  const int tid = threadIdx.x, b = blockIdx.x;
  const int wave = tid >> 6, lane = tid & 63;
  __shared__ __align__(16) float Mlds[16 * 2048];  // 128 KB: this block's 16 rows
  __shared__ __align__(16) float VA[2048];
  __shared__ __align__(16) float VB[2048];
  __shared__ float red[8];
  __shared__ float al[LK + 2], b2[LK + 2];
  __shared__ float bnds[2], res[2];

  // stage M rows first: 8 waves x 16 issues x 1 KB, contiguous 128 KB; the
  // global->LDS latency overlaps the v1 hash init; first __syncthreads drains.
  const float* Mblk = M + (size_t)b * 16 * 2048;
#pragma unroll
  for (int q = 0; q < 16; ++q)
    __builtin_amdgcn_global_load_lds(AS1C(Mblk + wave * 4096 + q * 256 + lane * 4),
                                     AS3(Mlds + wave * 4096 + q * 256), 16, 0, 0);

  // block-redundant init: v1 = hash / ||hash||  (identical in every block), v0 = 0
  float pv[4];
  float part = 0.f;
#pragma unroll
  for (int t = 0; t < 4; ++t) {
    int i = t * 512 + tid;
    unsigned u = (unsigned)i * 2654435761u;
    u ^= u >> 16; u *= 2246822519u; u ^= u >> 13;
    float rv = (float)(u >> 8) * (2.f / 16777216.f) - 1.f;
    pv[t] = rv;
    part += rv * rv;
  }
  float nrm = block_sum8(part, red);
  float innm = rsqrtf(nrm);
#pragma unroll
  for (int t = 0; t < 4; ++t) {
    int i = t * 512 + tid;
    VA[i] = pv[t] * innm;
    VB[i] = 0.f;
  }
  __syncthreads();

  float* Vcur = VA;
  float* Vprev = VB;
  float beta_prev = 0.f;

  for (int j = 1; j <= LK; ++j) {
    unsigned long long* Z = (j & 1) ? Z0 : Z1;
    // --- this block's 16 rows of z = M v_j - beta_{j-1} v_{j-1} (all-LDS Mv);
    //     each wave publishes its 2 rows as soon as they're done (early pub) ---
#pragma unroll
    for (int rr = 0; rr < 2; ++rr) {
      const int r = b * 16 + wave * 2 + rr;
      const float4* Mr = (const float4*)(Mlds + (wave * 2 + rr) * 2048);
      float s = 0.f;
#pragma unroll
      for (int t = 0; t < 8; ++t) {
        int idx = t * 64 + lane;
        float4 m4 = Mr[idx];
        float4 v4 = ((const float4*)Vcur)[idx];
        s += m4.x * v4.x + m4.y * v4.y + m4.z * v4.z + m4.w * v4.w;
      }
#pragma unroll
      for (int off = 32; off; off >>= 1) s += __shfl_down(s, off);
      if (lane == 0) {
        float zv = s - beta_prev * Vprev[r];
        unsigned long long pk = ((unsigned long long)(unsigned)j << 32) |
                                (unsigned long long)(unsigned)__float_as_uint(zv);
        __hip_atomic_store(&Z[r], pk, __ATOMIC_RELAXED, AGENT);
      }
    }

    // hoist own v-slice reads (LDS) ahead of the poll — free overlap
    float va[4];
#pragma unroll
    for (int t = 0; t < 4; ++t) va[t] = Vcur[t * 512 + tid];

    // --- poll own 4 Z words until their epoch == j (single-phase, fused
    //     data+flag); batched issue (one waitcnt) + capped-exp backoff ---
    unsigned long long w4[4];
    int rounds = 0;
    for (;;) {
      bool ok = true;
#pragma unroll
      for (int t = 0; t < 4; ++t) {
        w4[t] = __hip_atomic_load(&Z[t * 512 + tid], __ATOMIC_RELAXED, AGENT);
        ok &= ((unsigned)(w4[t] >> 32) == (unsigned)j);
      }
      if (ok) break;
      // capped-exponential backoff; s_sleep wants a literal immediate
      if (rounds == 1)      __builtin_amdgcn_s_sleep(1);   //  64 clk
      else if (rounds == 2) __builtin_amdgcn_s_sleep(2);   // 128 clk
      else if (rounds >= 3) __builtin_amdgcn_s_sleep(8);   // 512 clk
      ++rounds;
    }
    // --- redundant deterministic scalars, DIRECT beta form (Rule 2) ---
    float za[4];
    float pa = 0.f;
#pragma unroll
    for (int t = 0; t < 4; ++t) {
      za[t] = __uint_as_float((unsigned)w4[t]);
      pa += za[t] * va[t];
    }
    float alpha = block_sum8(pa, red);
    float pb = 0.f;
#pragma unroll
    for (int t = 0; t < 4; ++t) {
      float rsd = za[t] - alpha * va[t];
      pb += rsd * rsd;
    }
    float beta2 = block_sum8(pb, red);
    float beta = sqrtf(fmaxf(beta2, 1e-30f));
    float invb = 1.f / beta;
    if (tid == 0) { al[j] = alpha; b2[j] = beta2; }
    // rotate: overwrite Vprev storage (v_{j-1} dead) with v_{j+1}
#pragma unroll
    for (int t = 0; t < 4; ++t) {
      int i = t * 512 + tid;
      Vprev[i] = (za[t] - alpha * va[t]) * invb;
    }
    float* tmp = Vprev; Vprev = Vcur; Vcur = tmp;
    beta_prev = beta;
    __syncthreads();
  }

  // ---- extreme eigenvalues of T via Sturm bisection (block 0) ----
  if (b == 0) {
    if (tid == 0) {                                  // Gershgorin bounds on T
      float lo = 1e30f, hi = -1e30f;
      for (int i = 1; i <= LK; ++i) {
        float bl = (i > 1) ? sqrtf(b2[i - 1]) : 0.f;
        float br = (i < LK) ? sqrtf(b2[i]) : 0.f;
        lo = fminf(lo, al[i] - bl - br);
        hi = fmaxf(hi, al[i] + bl + br);
      }
      bnds[0] = lo; bnds[1] = hi;
    }
    __syncthreads();
    if (wave < 2) {                 // wave 0 -> lambda_min, wave 1 -> lambda_max
      const int tcount = (wave == 0) ? 1 : LK;
      float lo = bnds[0], hi = bnds[1];
      for (int round = 0; round < 4; ++round) {
        float x = lo + (hi - lo) * (float)(lane + 1) * (1.f / 65.f);
        int cnt = 0;                                 // #eigs of T below x
        float d = al[1] - x;
        if (fabsf(d) < 1e-25f) d = -1e-25f;
        if (d < 0.f) cnt++;
        for (int i = 2; i <= LK; ++i) {
          d = (al[i] - x) - b2[i - 1] / d;
          if (fabsf(d) < 1e-25f) d = -1e-25f;
          if (d < 0.f) cnt++;
        }
        bool ab = (cnt >= tcount);                   // x is above the target eig
        float cand_hi = ab ? x : hi;
        float cand_lo = ab ? lo : x;
#pragma unroll
        for (int off = 32; off; off >>= 1) {
          cand_hi = fminf(cand_hi, __shfl_down(cand_hi, off));
          cand_lo = fmaxf(cand_lo, __shfl_down(cand_lo, off));
        }
        cand_hi = __shfl(cand_hi, 0);
        cand_lo = __shfl(cand_lo, 0);
        hi = cand_hi;
        lo = fminf(cand_lo, hi);
      }
      if (lane == 0) res[wave] = 0.5f * (lo + hi);
    }
    __syncthreads();
    if (tid == 0) {
      float lmin = fmaxf(res[0], 1e-12f);
      float lmax = fmaxf(res[1], 1e-12f);
      out[0] = logf(lmax) - logf(lmin);
    }
  }
}

extern "C" void kernel_launch(void* const* d_in, const int* in_sizes, int n_in,
                              void* d_out, int out_size, void* d_ws, size_t ws_size,
                              hipStream_t stream) {
  const float* pred = (const float*)d_in[0];
  const float* scal = (const float*)d_in[1];
  const float* W    = (const float*)d_in[2];
  const int*   rows = (const int*)d_in[3];
  const int*   cols = (const int*)d_in[4];
  float* out = (float*)d_out;

  // workspace layout (peak ~49.1 MB):
  //  [0,16MB)  : Hf fp16 (8MB) during GEMM, then Ft (16MB)
  //  [16,32MB) : F
  //  [32,48MB) : A (written directly by GEMM), updated in place into M
  //  [48MB,..) : cnt, fixed-stride bins, epoch-tagged Z ping-pong
  char* ws = (char*)d_ws;
  const size_t MB = 1024 * 1024;
  unsigned short* Hf = (unsigned short*)(ws);
  float* F  = (float*)(ws + 16 * MB);
  float* A  = (float*)(ws + 32 * MB);
  float* Ft = (float*)(ws);             // reuses Hf (dead after gemm)
  char* ctrl = ws + 48 * MB;
  unsigned* cnt  = (unsigned*)(ctrl);                    //  8 KB (zeroed by convert)
  int*      bcol = (int*)(ctrl + 8192);                  //  512 KB (2048 x 64)
  float*    bval = (float*)(ctrl + 8192 + 524288);       //  512 KB
  unsigned long long* Z0 = (unsigned long long*)(ctrl + 8192 + 1048576);         // 16 KB
  unsigned long long* Z1 = (unsigned long long*)(ctrl + 8192 + 1048576 + 16384); // 16 KB

  convert_kernel<<<4096, 256, 0, stream>>>(W, Hf, cnt);
  // GEMM (split-K in-block) + fused fill
  gemm_f16_kernel<<<512, 512, 0, stream>>>(Hf, A, pred, scal, rows, cols, cnt, bcol, bval);

  gatherF_kernel<<<2048, 256, 0, stream>>>(cnt, bcol, bval, A, F);   // F = S*A
  addsym_kernel<<<dim3(64, 64), 256, 0, stream>>>(F, A, Ft);         // M = A+F+F^T; Ft=F^T
  gatherM_kernel<<<2048, 256, 0, stream>>>(cnt, bcol, bval, Ft, A);  // M += S*F^T

  // plain launch — 128 blocks x 512 threads, 147KB LDS => 1 block/CU, all resident
  lanczos_kernel<<<NBL, 512, 0, stream>>>(A, Z0, Z1, out);
}

// Round 6
// 264.953 us; speedup vs baseline: 1.1788x; 1.1740x over previous
//
#include <hip/hip_runtime.h>

// Problem constants (fixed by the reference)
#define N2 2048
#define NNZ 32768
#define LK 22          // FROZEN: absmax 0.0234 of 0.037 threshold (3 of ~4.7 bf16 ulps)
#define NBL 128        // lanczos grid blocks: 128 x 512 thr; 147KB LDS -> 1 block/CU
#define BINCAP 64      // slots per row bin (Poisson(16) tail ~1e-15)

typedef __attribute__((ext_vector_type(8))) _Float16 half8;
typedef __attribute__((ext_vector_type(4))) float f32x4;

#define AGENT __HIP_MEMORY_SCOPE_AGENT
#define AS1C(p) ((const __attribute__((address_space(1))) unsigned int*)(p))
#define AS3(p)  ((__attribute__((address_space(3))) unsigned int*)(p))

__device__ __forceinline__ unsigned short f2h(float f) {
  _Float16 h = (_Float16)f;                   // fp16 RNE
  return *(unsigned short*)&h;
}
__device__ __forceinline__ float h2f(unsigned short u) {
  _Float16 h = *(_Float16*)&u;
  return (float)h;
}

// ---- 1. W (fp32) -> fp16  (+ zero cnt for the binning pass) ----
__global__ __launch_bounds__(256) void convert_kernel(const float* __restrict__ W,
                                                      unsigned short* __restrict__ Hf,
                                                      unsigned* __restrict__ cnt) {
  if (blockIdx.x < 8) cnt[blockIdx.x * 256 + threadIdx.x] = 0;
  int i4 = blockIdx.x * 256 + threadIdx.x;          // grid 4096 -> 1048576 float4s
  float4 w = ((const float4*)W)[i4];
  ushort4 h;
  h.x = f2h(w.x); h.y = f2h(w.y); h.z = f2h(w.z); h.w = f2h(w.w);
  ((ushort4*)Hf)[i4] = h;
}

// ---- 2. A = Hf*Hf^T/N + I   — split-K + fused fill (R20); A stored FP16 (R21).
// R21: the non-lanczos region is BW-modeled; A/F/Ft move to fp16 storage
// (fp32 accumulate everywhere) to halve gather traffic. M stays fp32.
__global__ __launch_bounds__(512) void gemm_f16_kernel(const unsigned short* __restrict__ Hf,
                                                       unsigned short* __restrict__ Ah,
                                                       const float* __restrict__ pred,
                                                       const float* __restrict__ scal,
                                                       const int* __restrict__ rows,
                                                       const int* __restrict__ cols,
                                                       unsigned* __restrict__ cnt,
                                                       int* __restrict__ bcol,
                                                       float* __restrict__ bval) {
  const int tid = threadIdx.x;
  // ---- fused fill: 64 blocks x 512 threads cover NNZ=32768 ----
  if (blockIdx.x < 64) {
    int k = blockIdx.x * 512 + tid;
    int r = rows[k];
    unsigned pos = atomicAdd(&cnt[r], 1u);
    if (pos < BINCAP) {                     // Poisson(16) tail guard, ~never taken
      bcol[r * BINCAP + pos] = cols[k];
      bval[r * BINCAP + pos] = pred[k] * scal[k];
    }
  }

  __shared__ unsigned short Xs[2][64 * 32];
  __shared__ unsigned short Ys[2][128 * 32];
  __shared__ float Cred[64 * 132];          // pad 128->132: 2-way banks (free)
  const int w = tid >> 6, lane = tid & 63;
  const int half = w >> 2, wq = w & 3;      // k-half, role within half
  const int bi = blockIdx.x >> 4, bj = blockIdx.x & 15;   // 32 x 16 tiles
  const int row0 = bi * 64, col0 = bj * 128;
  const int m0 = (wq & 1) * 32, n0 = (wq >> 1) * 64;
  f32x4 acc[2][4];
#pragma unroll
  for (int a = 0; a < 2; ++a)
#pragma unroll
    for (int b = 0; b < 4; ++b) acc[a][b] = (f32x4){0.f, 0.f, 0.f, 0.f};
  const int mrow = lane & 15, kseg = (lane >> 4) * 8;
  const int srowX = wq * 16 + (lane >> 2);          // Xs: 16 rows/wave
  const int srowY = wq * 32 + (lane >> 2);          // Ys: 32 rows/wave (2 issues)
  const int scol = (lane & 3) * 8;
  const int kbase = half * 1024;

  for (int k0 = 0; k0 < 1024; k0 += 32) {
    __syncthreads();
    __builtin_amdgcn_global_load_lds(
        AS1C(Hf + (size_t)(row0 + srowX) * 2048 + kbase + k0 + scol),
        AS3(Xs[half] + (wq * 16) * 32), 16, 0, 0);
#pragma unroll
    for (int q = 0; q < 2; ++q) {
      __builtin_amdgcn_global_load_lds(
          AS1C(Hf + (size_t)(col0 + srowY + q * 16) * 2048 + kbase + k0 + scol),
          AS3(Ys[half] + (wq * 32 + q * 16) * 32), 16, 0, 0);
    }
    __syncthreads();
    half8 af[2], bf[4];
#pragma unroll
    for (int t = 0; t < 2; ++t)
      af[t] = *(const half8*)(Xs[half] + (m0 + t * 16 + mrow) * 32 + kseg);
#pragma unroll
    for (int t = 0; t < 4; ++t)
      bf[t] = *(const half8*)(Ys[half] + (n0 + t * 16 + mrow) * 32 + kseg);
#pragma unroll
    for (int mt = 0; mt < 2; ++mt)
#pragma unroll
      for (int nt = 0; nt < 4; ++nt)
        acc[mt][nt] = __builtin_amdgcn_mfma_f32_16x16x32_f16(af[mt], bf[nt], acc[mt][nt], 0, 0, 0);
  }
  // ---- combine halves: high -> LDS, low adds and stores fp16 A ----
  // C/D layout: col = lane&15, row = (lane>>4)*4 + reg   [m89-verified]
  const int crow = (lane >> 4) * 4, ccol = lane & 15;
  __syncthreads();
  if (half == 1) {
#pragma unroll
    for (int mt = 0; mt < 2; ++mt)
#pragma unroll
      for (int nt = 0; nt < 4; ++nt)
#pragma unroll
        for (int r = 0; r < 4; ++r)
          Cred[(m0 + mt * 16 + crow + r) * 132 + n0 + nt * 16 + ccol] = acc[mt][nt][r];
  }
  __syncthreads();
  if (half == 0) {
    const float invn = 1.0f / 2048.0f;
#pragma unroll
    for (int mt = 0; mt < 2; ++mt)
#pragma unroll
      for (int nt = 0; nt < 4; ++nt) {
        const int gi0 = row0 + m0 + mt * 16 + crow;
        const int gj = col0 + n0 + nt * 16 + ccol;
        size_t base = (size_t)gi0 * 2048 + gj;
#pragma unroll
        for (int r = 0; r < 4; ++r) {
          float v = acc[mt][nt][r] +
                    Cred[(m0 + mt * 16 + crow + r) * 132 + n0 + nt * 16 + ccol];
          Ah[base + (size_t)r * 2048] = f2h(v * invn + ((gi0 + r == gj) ? 1.0f : 0.0f));
        }
      }
  }
}

// ---- 4d. F[r,:] = sum_e val_e * A[col_e,:]  (fp16 in/out, fp32 accum) ----
__global__ __launch_bounds__(256) void gatherF_kernel(const unsigned* __restrict__ cnt,
                                                      const int* __restrict__ bcol,
                                                      const float* __restrict__ bval,
                                                      const unsigned short* __restrict__ Ah,
                                                      unsigned short* __restrict__ F) {
  const int r = blockIdx.x, tid = threadIdx.x;
  float acc[8] = {0.f, 0.f, 0.f, 0.f, 0.f, 0.f, 0.f, 0.f};
  const unsigned ne = min(cnt[r], (unsigned)BINCAP);
  for (unsigned e = 0; e < ne; ++e) {
    const float v = bval[r * BINCAP + e];
    uint4 raw = ((const uint4*)(Ah + (size_t)bcol[r * BINCAP + e] * 2048))[tid];
    half8 hv = *(half8*)&raw;
#pragma unroll
    for (int k = 0; k < 8; ++k) acc[k] += v * (float)hv[k];
  }
  unsigned short o[8];
#pragma unroll
  for (int k = 0; k < 8; ++k) o[k] = f2h(acc[k]);
  *(uint4*)(F + (size_t)r * 2048 + tid * 8) = *(uint4*)o;
}

// ---- 5. M(fp32) = A + F + F^T;  Ft(fp16) = F^T   (64x64 tiles) ----
__global__ __launch_bounds__(256) void addsym_kernel(const unsigned short* __restrict__ F,
                                                     const unsigned short* __restrict__ Ah,
                                                     float* __restrict__ M,
                                                     unsigned short* __restrict__ Ft) {
  __shared__ unsigned short T2[64][66];     // stride 132B: 4B-aligned, read-spread
  const int bi = blockIdx.x, bj = blockIdx.y;
  const int c8 = (threadIdx.x & 7) * 8;     // col offset in halves (0..56)
  const int rr = threadIdx.x >> 3;          // 0..31
#pragma unroll
  for (int h = 0; h < 2; ++h) {
    const int r = rr + h * 32;
    uint4 raw = *(const uint4*)(F + (size_t)(bj * 64 + r) * 2048 + bi * 64 + c8);
    const unsigned* pw = (const unsigned*)&raw;
#pragma unroll
    for (int i = 0; i < 4; ++i)
      *(unsigned*)&T2[r][c8 + i * 2] = pw[i];
  }
  __syncthreads();
#pragma unroll
  for (int h = 0; h < 2; ++h) {
    const int r = rr + h * 32;
    const size_t off = (size_t)(bi * 64 + r) * 2048 + bj * 64 + c8;
    uint4 rf = *(const uint4*)(F + off);
    uint4 ra = *(const uint4*)(Ah + off);
    half8 hf = *(half8*)&rf;
    half8 ha = *(half8*)&ra;
    unsigned short tv[8];
    float out[8];
#pragma unroll
    for (int k = 0; k < 8; ++k) {
      unsigned short t = T2[c8 + k][r];     // F^T element (transposed read)
      tv[k] = t;
      out[k] = (float)ha[k] + ((float)hf[k] + h2f(t));
    }
    *(uint4*)(Ft + off) = *(uint4*)tv;
    float4* Mo = (float4*)(M + off);
    Mo[0] = (float4){out[0], out[1], out[2], out[3]};
    Mo[1] = (float4){out[4], out[5], out[6], out[7]};
  }
}

// ---- 4e. M[r,:] += sum_e val_e * Ft[col_e,:]  (fp16 gathers, fp32 M) ----
__global__ __launch_bounds__(256) void gatherM_kernel(const unsigned* __restrict__ cnt,
                                                      const int* __restrict__ bcol,
                                                      const float* __restrict__ bval,
                                                      const unsigned short* __restrict__ Ft,
                                                      float* __restrict__ M) {
  const int r = blockIdx.x, tid = threadIdx.x;
  float acc[8] = {0.f, 0.f, 0.f, 0.f, 0.f, 0.f, 0.f, 0.f};
  const unsigned ne = min(cnt[r], (unsigned)BINCAP);
  for (unsigned e = 0; e < ne; ++e) {
    const float v = bval[r * BINCAP + e];
    uint4 raw = ((const uint4*)(Ft + (size_t)bcol[r * BINCAP + e] * 2048))[tid];
    half8 hv = *(half8*)&raw;
#pragma unroll
    for (int k = 0; k < 8; ++k) acc[k] += v * (float)hv[k];
  }
  float4* Mr = (float4*)(M + (size_t)r * 2048 + tid * 8);
  float4 m0 = Mr[0], m1 = Mr[1];
  m0.x += acc[0]; m0.y += acc[1]; m0.z += acc[2]; m0.w += acc[3];
  m1.x += acc[4]; m1.y += acc[5]; m1.z += acc[6]; m1.w += acc[7];
  Mr[0] = m0;
  Mr[1] = m1;
}

// ---- deterministic block-wide sum over 8 waves: bitwise-identical per block ----
__device__ __forceinline__ float block_sum8(float v, float* red) {
#pragma unroll
  for (int off = 32; off; off >>= 1) v += __shfl_down(v, off);
  if ((threadIdx.x & 63) == 0) red[threadIdx.x >> 6] = v;
  __syncthreads();
  float r = ((red[0] + red[1]) + (red[2] + red[3])) +
            ((red[4] + red[5]) + (red[6] + red[7]));
  __syncthreads();
  return r;
}

// ---- 6. Lanczos: single-phase epoch protocol, 128 x 512 — FROZEN (R20) ----
// R20: ~4.2 us/iter exchange is the store->remote-observability floor of an
// agent-scope publish under polling — robust to protocol shape (R0/R1/R3),
// traffic volume (R3 backoff), and agent count (R4). Do not retune.
// RULE 1 (R1/R6): cross-block data via agent-scope atomics only.
// RULE 2 (R1/R6/R8): beta^2 = ||z - alpha v||^2 DIRECT form only.
// RULE 3 (R16): no fixed-address staging reuse with plain cached loads.
// RULE 4 (R17): exactly ONE publish->consume phase per iteration.
// RULE 5 (R19/R20): exchange cost is per-phase visibility latency.
__global__ __launch_bounds__(512) void lanczos_kernel(const float* __restrict__ M,
                                                      unsigned long long* __restrict__ Z0,
                                                      unsigned long long* __restrict__ Z1,
                                                      float* __restrict__ out) {
  const int tid = threadIdx.x, b = blockIdx.x;
  const int wave = tid >> 6, lane = tid & 63;
  __shared__ __align__(16) float Mlds[16 * 2048];  // 128 KB: this block's 16 rows
  __shared__ __align__(16) float VA[2048];
  __shared__ __align__(16) float VB[2048];
  __shared__ float red[8];
  __shared__ float al[LK + 2], b2[LK + 2];
  __shared__ float bnds[2], res[2];

  const float* Mblk = M + (size_t)b * 16 * 2048;
#pragma unroll
  for (int q = 0; q < 16; ++q)
    __builtin_amdgcn_global_load_lds(AS1C(Mblk + wave * 4096 + q * 256 + lane * 4),
                                     AS3(Mlds + wave * 4096 + q * 256), 16, 0, 0);

  // block-redundant init: v1 = hash / ||hash||  (identical in every block), v0 = 0
  float pv[4];
  float part = 0.f;
#pragma unroll
  for (int t = 0; t < 4; ++t) {
    int i = t * 512 + tid;
    unsigned u = (unsigned)i * 2654435761u;
    u ^= u >> 16; u *= 2246822519u; u ^= u >> 13;
    float rv = (float)(u >> 8) * (2.f / 16777216.f) - 1.f;
    pv[t] = rv;
    part += rv * rv;
  }
  float nrm = block_sum8(part, red);
  float innm = rsqrtf(nrm);
#pragma unroll
  for (int t = 0; t < 4; ++t) {
    int i = t * 512 + tid;
    VA[i] = pv[t] * innm;
    VB[i] = 0.f;
  }
  __syncthreads();

  float* Vcur = VA;
  float* Vprev = VB;
  float beta_prev = 0.f;

  for (int j = 1; j <= LK; ++j) {
    unsigned long long* Z = (j & 1) ? Z0 : Z1;
#pragma unroll
    for (int rr = 0; rr < 2; ++rr) {
      const int r = b * 16 + wave * 2 + rr;
      const float4* Mr = (const float4*)(Mlds + (wave * 2 + rr) * 2048);
      float s = 0.f;
#pragma unroll
      for (int t = 0; t < 8; ++t) {
        int idx = t * 64 + lane;
        float4 m4 = Mr[idx];
        float4 v4 = ((const float4*)Vcur)[idx];
        s += m4.x * v4.x + m4.y * v4.y + m4.z * v4.z + m4.w * v4.w;
      }
#pragma unroll
      for (int off = 32; off; off >>= 1) s += __shfl_down(s, off);
      if (lane == 0) {
        float zv = s - beta_prev * Vprev[r];
        unsigned long long pk = ((unsigned long long)(unsigned)j << 32) |
                                (unsigned long long)(unsigned)__float_as_uint(zv);
        __hip_atomic_store(&Z[r], pk, __ATOMIC_RELAXED, AGENT);
      }
    }

    // hoist own v-slice reads (LDS) ahead of the poll — free overlap
    float va[4];
#pragma unroll
    for (int t = 0; t < 4; ++t) va[t] = Vcur[t * 512 + tid];

    unsigned long long w4[4];
    int rounds = 0;
    for (;;) {
      bool ok = true;
#pragma unroll
      for (int t = 0; t < 4; ++t) {
        w4[t] = __hip_atomic_load(&Z[t * 512 + tid], __ATOMIC_RELAXED, AGENT);
        ok &= ((unsigned)(w4[t] >> 32) == (unsigned)j);
      }
      if (ok) break;
      if (rounds == 1)      __builtin_amdgcn_s_sleep(1);   //  64 clk
      else if (rounds == 2) __builtin_amdgcn_s_sleep(2);   // 128 clk
      else if (rounds >= 3) __builtin_amdgcn_s_sleep(8);   // 512 clk
      ++rounds;
    }
    float za[4];
    float pa = 0.f;
#pragma unroll
    for (int t = 0; t < 4; ++t) {
      za[t] = __uint_as_float((unsigned)w4[t]);
      pa += za[t] * va[t];
    }
    float alpha = block_sum8(pa, red);
    float pb = 0.f;
#pragma unroll
    for (int t = 0; t < 4; ++t) {
      float rsd = za[t] - alpha * va[t];
      pb += rsd * rsd;
    }
    float beta2 = block_sum8(pb, red);
    float beta = sqrtf(fmaxf(beta2, 1e-30f));
    float invb = 1.f / beta;
    if (tid == 0) { al[j] = alpha; b2[j] = beta2; }
#pragma unroll
    for (int t = 0; t < 4; ++t) {
      int i = t * 512 + tid;
      Vprev[i] = (za[t] - alpha * va[t]) * invb;
    }
    float* tmp = Vprev; Vprev = Vcur; Vcur = tmp;
    beta_prev = beta;
    __syncthreads();
  }

  // ---- extreme eigenvalues of T via Sturm bisection (block 0) ----
  if (b == 0) {
    if (tid == 0) {                                  // Gershgorin bounds on T
      float lo = 1e30f, hi = -1e30f;
      for (int i = 1; i <= LK; ++i) {
        float bl = (i > 1) ? sqrtf(b2[i - 1]) : 0.f;
        float br = (i < LK) ? sqrtf(b2[i]) : 0.f;
        lo = fminf(lo, al[i] - bl - br);
        hi = fmaxf(hi, al[i] + bl + br);
      }
      bnds[0] = lo; bnds[1] = hi;
    }
    __syncthreads();
    if (wave < 2) {                 // wave 0 -> lambda_min, wave 1 -> lambda_max
      const int tcount = (wave == 0) ? 1 : LK;
      float lo = bnds[0], hi = bnds[1];
      for (int round = 0; round < 4; ++round) {
        float x = lo + (hi - lo) * (float)(lane + 1) * (1.f / 65.f);
        int cnt = 0;                                 // #eigs of T below x
        float d = al[1] - x;
        if (fabsf(d) < 1e-25f) d = -1e-25f;
        if (d < 0.f) cnt++;
        for (int i = 2; i <= LK; ++i) {
          d = (al[i] - x) - b2[i - 1] / d;
          if (fabsf(d) < 1e-25f) d = -1e-25f;
          if (d < 0.f) cnt++;
        }
        bool ab = (cnt >= tcount);                   // x is above the target eig
        float cand_hi = ab ? x : hi;
        float cand_lo = ab ? lo : x;
#pragma unroll
        for (int off = 32; off; off >>= 1) {
          cand_hi = fminf(cand_hi, __shfl_down(cand_hi, off));
          cand_lo = fmaxf(cand_lo, __shfl_down(cand_lo, off));
        }
        cand_hi = __shfl(cand_hi, 0);
        cand_lo = __shfl(cand_lo, 0);
        hi = cand_hi;
        lo = fminf(cand_lo, hi);
      }
      if (lane == 0) res[wave] = 0.5f * (lo + hi);
    }
    __syncthreads();
    if (tid == 0) {
      float lmin = fmaxf(res[0], 1e-12f);
      float lmax = fmaxf(res[1], 1e-12f);
      out[0] = logf(lmax) - logf(lmin);
    }
  }
}

extern "C" void kernel_launch(void* const* d_in, const int* in_sizes, int n_in,
                              void* d_out, int out_size, void* d_ws, size_t ws_size,
                              hipStream_t stream) {
  const float* pred = (const float*)d_in[0];
  const float* scal = (const float*)d_in[1];
  const float* W    = (const float*)d_in[2];
  const int*   rows = (const int*)d_in[3];
  const int*   cols = (const int*)d_in[4];
  float* out = (float*)d_out;

  // workspace layout (peak ~41.1 MB):
  //  [0,8MB)   : Hf fp16 (dead after gemm) -> Ft fp16
  //  [8,16MB)  : A fp16
  //  [16,24MB) : F fp16
  //  [24,40MB) : M fp32
  //  [40MB,..) : cnt, fixed-stride bins, epoch-tagged Z ping-pong
  char* ws = (char*)d_ws;
  const size_t MB = 1024 * 1024;
  unsigned short* Hf = (unsigned short*)(ws);
  unsigned short* Ah = (unsigned short*)(ws + 8 * MB);
  unsigned short* F  = (unsigned short*)(ws + 16 * MB);
  unsigned short* Ft = (unsigned short*)(ws);          // reuses Hf (dead after gemm)
  float* M = (float*)(ws + 24 * MB);
  char* ctrl = ws + 40 * MB;
  unsigned* cnt  = (unsigned*)(ctrl);                    //  8 KB (zeroed by convert)
  int*      bcol = (int*)(ctrl + 8192);                  //  512 KB (2048 x 64)
  float*    bval = (float*)(ctrl + 8192 + 524288);       //  512 KB
  unsigned long long* Z0 = (unsigned long long*)(ctrl + 8192 + 1048576);         // 16 KB
  unsigned long long* Z1 = (unsigned long long*)(ctrl + 8192 + 1048576 + 16384); // 16 KB

  convert_kernel<<<4096, 256, 0, stream>>>(W, Hf, cnt);
  // GEMM (split-K) + fused fill; writes A fp16
  gemm_f16_kernel<<<512, 512, 0, stream>>>(Hf, Ah, pred, scal, rows, cols, cnt, bcol, bval);

  gatherF_kernel<<<2048, 256, 0, stream>>>(cnt, bcol, bval, Ah, F);    // F = S*A (fp16)
  addsym_kernel<<<dim3(32, 32), 256, 0, stream>>>(F, Ah, M, Ft);       // M = A+F+F^T; Ft=F^T
  gatherM_kernel<<<2048, 256, 0, stream>>>(cnt, bcol, bval, Ft, M);    // M += S*F^T

  // plain launch — 128 blocks x 512 threads, 147KB LDS => 1 block/CU, all resident
  lanczos_kernel<<<NBL, 512, 0, stream>>>(M, Z0, Z1, out);
}

// Round 7
// 256.452 us; speedup vs baseline: 1.2179x; 1.0332x over previous
//
#include <hip/hip_runtime.h>

// Problem constants (fixed by the reference)
#define N2 2048
#define NNZ 32768
#define LK 22          // FROZEN: absmax 0.0234 of 0.037 threshold (3 of ~4.7 bf16 ulps)
#define NBL 128        // lanczos grid blocks: 128 x 512 thr; 147KB LDS -> 1 block/CU
#define BINCAP 64      // slots per row bin (Poisson(16) tail ~1e-15)

typedef __attribute__((ext_vector_type(8))) _Float16 half8;
typedef __attribute__((ext_vector_type(4))) float f32x4;

#define AGENT __HIP_MEMORY_SCOPE_AGENT
#define AS1C(p) ((const __attribute__((address_space(1))) unsigned int*)(p))
#define AS3(p)  ((__attribute__((address_space(3))) unsigned int*)(p))

__device__ __forceinline__ unsigned short f2h(float f) {
  _Float16 h = (_Float16)f;                   // fp16 RNE
  return *(unsigned short*)&h;
}
__device__ __forceinline__ float h2f(unsigned short u) {
  _Float16 h = *(_Float16*)&u;
  return (float)h;
}

// ---- 1. W (fp32) -> fp16  (+ zero cnt for the binning pass) ----
__global__ __launch_bounds__(256) void convert_kernel(const float* __restrict__ W,
                                                      unsigned short* __restrict__ Hf,
                                                      unsigned* __restrict__ cnt) {
  if (blockIdx.x < 8) cnt[blockIdx.x * 256 + threadIdx.x] = 0;
  int i4 = blockIdx.x * 256 + threadIdx.x;          // grid 4096 -> 1048576 float4s
  float4 w = ((const float4*)W)[i4];
  ushort4 h;
  h.x = f2h(w.x); h.y = f2h(w.y); h.z = f2h(w.z); h.w = f2h(w.w);
  ((ushort4*)Hf)[i4] = h;
}

// ---- 2. A = Hf*Hf^T/N + I   — split-K + fused fill (R20); A fp16 (R21);
//         XCD-swizzled tiles (R22): grid 512 = 64/XCD, swz=(b&7)*64+(b>>3)
//         bijective; each XCD works a contiguous 4-row band of tiles so the
//         Hf panel re-reads (~400MB streamed from an 8MB array) hit its L2.
__global__ __launch_bounds__(512) void gemm_f16_kernel(const unsigned short* __restrict__ Hf,
                                                       unsigned short* __restrict__ Ah,
                                                       const float* __restrict__ pred,
                                                       const float* __restrict__ scal,
                                                       const int* __restrict__ rows,
                                                       const int* __restrict__ cols,
                                                       unsigned* __restrict__ cnt,
                                                       int* __restrict__ bcol,
                                                       float* __restrict__ bval) {
  const int tid = threadIdx.x;
  // ---- fused fill: 64 blocks x 512 threads cover NNZ=32768 (raw blockIdx) ----
  if (blockIdx.x < 64) {
    int k = blockIdx.x * 512 + tid;
    int r = rows[k];
    unsigned pos = atomicAdd(&cnt[r], 1u);
    if (pos < BINCAP) {                     // Poisson(16) tail guard, ~never taken
      bcol[r * BINCAP + pos] = cols[k];
      bval[r * BINCAP + pos] = pred[k] * scal[k];
    }
  }

  __shared__ unsigned short Xs[2][64 * 32];
  __shared__ unsigned short Ys[2][128 * 32];
  __shared__ float Cred[64 * 132];          // pad 128->132: 2-way banks (free)
  const int w = tid >> 6, lane = tid & 63;
  const int half = w >> 2, wq = w & 3;      // k-half, role within half
  const int swz = ((blockIdx.x & 7) << 6) | (blockIdx.x >> 3);   // XCD swizzle
  const int bi = swz >> 4, bj = swz & 15;   // 32 x 16 tiles
  const int row0 = bi * 64, col0 = bj * 128;
  const int m0 = (wq & 1) * 32, n0 = (wq >> 1) * 64;
  f32x4 acc[2][4];
#pragma unroll
  for (int a = 0; a < 2; ++a)
#pragma unroll
    for (int b = 0; b < 4; ++b) acc[a][b] = (f32x4){0.f, 0.f, 0.f, 0.f};
  const int mrow = lane & 15, kseg = (lane >> 4) * 8;
  const int srowX = wq * 16 + (lane >> 2);          // Xs: 16 rows/wave
  const int srowY = wq * 32 + (lane >> 2);          // Ys: 32 rows/wave (2 issues)
  const int scol = (lane & 3) * 8;
  const int kbase = half * 1024;

  for (int k0 = 0; k0 < 1024; k0 += 32) {
    __syncthreads();
    __builtin_amdgcn_global_load_lds(
        AS1C(Hf + (size_t)(row0 + srowX) * 2048 + kbase + k0 + scol),
        AS3(Xs[half] + (wq * 16) * 32), 16, 0, 0);
#pragma unroll
    for (int q = 0; q < 2; ++q) {
      __builtin_amdgcn_global_load_lds(
          AS1C(Hf + (size_t)(col0 + srowY + q * 16) * 2048 + kbase + k0 + scol),
          AS3(Ys[half] + (wq * 32 + q * 16) * 32), 16, 0, 0);
    }
    __syncthreads();
    half8 af[2], bf[4];
#pragma unroll
    for (int t = 0; t < 2; ++t)
      af[t] = *(const half8*)(Xs[half] + (m0 + t * 16 + mrow) * 32 + kseg);
#pragma unroll
    for (int t = 0; t < 4; ++t)
      bf[t] = *(const half8*)(Ys[half] + (n0 + t * 16 + mrow) * 32 + kseg);
#pragma unroll
    for (int mt = 0; mt < 2; ++mt)
#pragma unroll
      for (int nt = 0; nt < 4; ++nt)
        acc[mt][nt] = __builtin_amdgcn_mfma_f32_16x16x32_f16(af[mt], bf[nt], acc[mt][nt], 0, 0, 0);
  }
  // ---- combine halves: high -> LDS, low adds and stores fp16 A ----
  // C/D layout: col = lane&15, row = (lane>>4)*4 + reg   [m89-verified]
  const int crow = (lane >> 4) * 4, ccol = lane & 15;
  __syncthreads();
  if (half == 1) {
#pragma unroll
    for (int mt = 0; mt < 2; ++mt)
#pragma unroll
      for (int nt = 0; nt < 4; ++nt)
#pragma unroll
        for (int r = 0; r < 4; ++r)
          Cred[(m0 + mt * 16 + crow + r) * 132 + n0 + nt * 16 + ccol] = acc[mt][nt][r];
  }
  __syncthreads();
  if (half == 0) {
    const float invn = 1.0f / 2048.0f;
#pragma unroll
    for (int mt = 0; mt < 2; ++mt)
#pragma unroll
      for (int nt = 0; nt < 4; ++nt) {
        const int gi0 = row0 + m0 + mt * 16 + crow;
        const int gj = col0 + n0 + nt * 16 + ccol;
        size_t base = (size_t)gi0 * 2048 + gj;
#pragma unroll
        for (int r = 0; r < 4; ++r) {
          float v = acc[mt][nt][r] +
                    Cred[(m0 + mt * 16 + crow + r) * 132 + n0 + nt * 16 + ccol];
          Ah[base + (size_t)r * 2048] = f2h(v * invn + ((gi0 + r == gj) ? 1.0f : 0.0f));
        }
      }
  }
}

// ---- 4d. F[r,:] = sum_e val_e * A[col_e,:]  (fp16, fp32 accum) ----
// R22: bin metadata staged in LDS; 4-way unrolled row loads (MLP 1 -> 4)
// to break the serial bcol->addr->load dependence chain.
__global__ __launch_bounds__(256) void gatherF_kernel(const unsigned* __restrict__ cnt,
                                                      const int* __restrict__ bcol,
                                                      const float* __restrict__ bval,
                                                      const unsigned short* __restrict__ Ah,
                                                      unsigned short* __restrict__ F) {
  const int r = blockIdx.x, tid = threadIdx.x;
  __shared__ int scol_[BINCAP];
  __shared__ float sval_[BINCAP];
  const unsigned ne = min(cnt[r], (unsigned)BINCAP);
  if (tid < ne) {
    scol_[tid] = bcol[r * BINCAP + tid];
    sval_[tid] = bval[r * BINCAP + tid];
  }
  __syncthreads();
  float acc[8] = {0.f, 0.f, 0.f, 0.f, 0.f, 0.f, 0.f, 0.f};
  unsigned e = 0;
  for (; e + 4 <= ne; e += 4) {
    uint4 q0 = *(const uint4*)(Ah + (size_t)scol_[e + 0] * 2048 + tid * 8);
    uint4 q1 = *(const uint4*)(Ah + (size_t)scol_[e + 1] * 2048 + tid * 8);
    uint4 q2 = *(const uint4*)(Ah + (size_t)scol_[e + 2] * 2048 + tid * 8);
    uint4 q3 = *(const uint4*)(Ah + (size_t)scol_[e + 3] * 2048 + tid * 8);
    half8 h0 = *(half8*)&q0, h1 = *(half8*)&q1, h2 = *(half8*)&q2, h3 = *(half8*)&q3;
    const float v0 = sval_[e], v1 = sval_[e + 1], v2 = sval_[e + 2], v3 = sval_[e + 3];
#pragma unroll
    for (int k = 0; k < 8; ++k) {
      acc[k] += v0 * (float)h0[k];
      acc[k] += v1 * (float)h1[k];
      acc[k] += v2 * (float)h2[k];
      acc[k] += v3 * (float)h3[k];
    }
  }
  for (; e < ne; ++e) {
    uint4 q = *(const uint4*)(Ah + (size_t)scol_[e] * 2048 + tid * 8);
    half8 hv = *(half8*)&q;
    const float v = sval_[e];
#pragma unroll
    for (int k = 0; k < 8; ++k) acc[k] += v * (float)hv[k];
  }
  unsigned short o[8];
#pragma unroll
  for (int k = 0; k < 8; ++k) o[k] = f2h(acc[k]);
  *(uint4*)(F + (size_t)r * 2048 + tid * 8) = *(uint4*)o;
}

// ---- 5a. Ft = F^T  (fp16, 64x64 tiles; same layout as R21 addsym) ----
__global__ __launch_bounds__(256) void transpose_kernel(const unsigned short* __restrict__ F,
                                                        unsigned short* __restrict__ Ft) {
  __shared__ unsigned short T2[64][66];     // stride 132B: 4B-aligned, read-spread
  const int bi = blockIdx.x, bj = blockIdx.y;
  const int c8 = (threadIdx.x & 7) * 8;
  const int rr = threadIdx.x >> 3;
#pragma unroll
  for (int h = 0; h < 2; ++h) {
    const int r = rr + h * 32;
    uint4 raw = *(const uint4*)(F + (size_t)(bj * 64 + r) * 2048 + bi * 64 + c8);
    const unsigned* pw = (const unsigned*)&raw;
#pragma unroll
    for (int i = 0; i < 4; ++i)
      *(unsigned*)&T2[r][c8 + i * 2] = pw[i];
  }
  __syncthreads();
#pragma unroll
  for (int h = 0; h < 2; ++h) {
    const int r = rr + h * 32;
    unsigned short tv[8];
#pragma unroll
    for (int k = 0; k < 8; ++k) tv[k] = T2[c8 + k][r];
    *(uint4*)(Ft + (size_t)(bi * 64 + r) * 2048 + bj * 64 + c8) = *(uint4*)tv;
  }
}

// ---- 5b. finalM: M[r,:] = A + F + Ft + sum_e val_e*Ft[col_e,:]  (ONE M pass)
// R22: fuses old addsym-M-update and gatherM; M written exactly once (16MB),
// killing the 32MB read-modify-write pass. Same LDS-staged 4-way MLP gather.
__global__ __launch_bounds__(256) void finalM_kernel(const unsigned* __restrict__ cnt,
                                                     const int* __restrict__ bcol,
                                                     const float* __restrict__ bval,
                                                     const unsigned short* __restrict__ Ah,
                                                     const unsigned short* __restrict__ F,
                                                     const unsigned short* __restrict__ Ft,
                                                     float* __restrict__ M) {
  const int r = blockIdx.x, tid = threadIdx.x;
  __shared__ int scol_[BINCAP];
  __shared__ float sval_[BINCAP];
  const unsigned ne = min(cnt[r], (unsigned)BINCAP);
  if (tid < ne) {
    scol_[tid] = bcol[r * BINCAP + tid];
    sval_[tid] = bval[r * BINCAP + tid];
  }
  __syncthreads();
  float acc[8] = {0.f, 0.f, 0.f, 0.f, 0.f, 0.f, 0.f, 0.f};
  unsigned e = 0;
  for (; e + 4 <= ne; e += 4) {
    uint4 q0 = *(const uint4*)(Ft + (size_t)scol_[e + 0] * 2048 + tid * 8);
    uint4 q1 = *(const uint4*)(Ft + (size_t)scol_[e + 1] * 2048 + tid * 8);
    uint4 q2 = *(const uint4*)(Ft + (size_t)scol_[e + 2] * 2048 + tid * 8);
    uint4 q3 = *(const uint4*)(Ft + (size_t)scol_[e + 3] * 2048 + tid * 8);
    half8 h0 = *(half8*)&q0, h1 = *(half8*)&q1, h2 = *(half8*)&q2, h3 = *(half8*)&q3;
    const float v0 = sval_[e], v1 = sval_[e + 1], v2 = sval_[e + 2], v3 = sval_[e + 3];
#pragma unroll
    for (int k = 0; k < 8; ++k) {
      acc[k] += v0 * (float)h0[k];
      acc[k] += v1 * (float)h1[k];
      acc[k] += v2 * (float)h2[k];
      acc[k] += v3 * (float)h3[k];
    }
  }
  for (; e < ne; ++e) {
    uint4 q = *(const uint4*)(Ft + (size_t)scol_[e] * 2048 + tid * 8);
    half8 hv = *(half8*)&q;
    const float v = sval_[e];
#pragma unroll
    for (int k = 0; k < 8; ++k) acc[k] += v * (float)hv[k];
  }
  // combine: M = A + F + Ft + acc   (single fp32 write pass)
  const size_t off = (size_t)r * 2048 + tid * 8;
  uint4 ra = *(const uint4*)(Ah + off);
  uint4 rf = *(const uint4*)(F + off);
  uint4 rt = *(const uint4*)(Ft + off);
  half8 ha = *(half8*)&ra, hf = *(half8*)&rf, ht = *(half8*)&rt;
  float out[8];
#pragma unroll
  for (int k = 0; k < 8; ++k)
    out[k] = (float)ha[k] + ((float)hf[k] + (float)ht[k]) + acc[k];
  float4* Mo = (float4*)(M + off);
  Mo[0] = (float4){out[0], out[1], out[2], out[3]};
  Mo[1] = (float4){out[4], out[5], out[6], out[7]};
}

// ---- deterministic block-wide sum over 8 waves: bitwise-identical per block ----
__device__ __forceinline__ float block_sum8(float v, float* red) {
#pragma unroll
  for (int off = 32; off; off >>= 1) v += __shfl_down(v, off);
  if ((threadIdx.x & 63) == 0) red[threadIdx.x >> 6] = v;
  __syncthreads();
  float r = ((red[0] + red[1]) + (red[2] + red[3])) +
            ((red[4] + red[5]) + (red[6] + red[7]));
  __syncthreads();
  return r;
}

// ---- 6. Lanczos: single-phase epoch protocol, 128 x 512 — FROZEN (R20) ----
// R20: ~4.2 us/iter exchange is the store->remote-observability floor of an
// agent-scope publish under polling — robust to protocol shape (R0/R1/R3),
// traffic volume (R3 backoff), and agent count (R4). Do not retune.
// RULE 1 (R1/R6): cross-block data via agent-scope atomics only.
// RULE 2 (R1/R6/R8): beta^2 = ||z - alpha v||^2 DIRECT form only.
// RULE 3 (R16): no fixed-address staging reuse with plain cached loads.
// RULE 4 (R17): exactly ONE publish->consume phase per iteration.
// RULE 5 (R19/R20): exchange cost is per-phase visibility latency.
__global__ __launch_bounds__(512) void lanczos_kernel(const float* __restrict__ M,
                                                      unsigned long long* __restrict__ Z0,
                                                      unsigned long long* __restrict__ Z1,
                                                      float* __restrict__ out) {
  const int tid = threadIdx.x, b = blockIdx.x;
  const int wave = tid >> 6, lane = tid & 63;
  __shared__ __align__(16) float Mlds[16 * 2048];  // 128 KB: this block's 16 rows
  __shared__ __align__(16) float VA[2048];
  __shared__ __align__(16) float VB[2048];
  __shared__ float red[8];
  __shared__ float al[LK + 2], b2[LK + 2];
  __shared__ float bnds[2], res[2];

  const float* Mblk = M + (size_t)b * 16 * 2048;
#pragma unroll
  for (int q = 0; q < 16; ++q)
    __builtin_amdgcn_global_load_lds(AS1C(Mblk + wave * 4096 + q * 256 + lane * 4),
                                     AS3(Mlds + wave * 4096 + q * 256), 16, 0, 0);

  // block-redundant init: v1 = hash / ||hash||  (identical in every block), v0 = 0
  float pv[4];
  float part = 0.f;
#pragma unroll
  for (int t = 0; t < 4; ++t) {
    int i = t * 512 + tid;
    unsigned u = (unsigned)i * 2654435761u;
    u ^= u >> 16; u *= 2246822519u; u ^= u >> 13;
    float rv = (float)(u >> 8) * (2.f / 16777216.f) - 1.f;
    pv[t] = rv;
    part += rv * rv;
  }
  float nrm = block_sum8(part, red);
  float innm = rsqrtf(nrm);
#pragma unroll
  for (int t = 0; t < 4; ++t) {
    int i = t * 512 + tid;
    VA[i] = pv[t] * innm;
    VB[i] = 0.f;
  }
  __syncthreads();

  float* Vcur = VA;
  float* Vprev = VB;
  float beta_prev = 0.f;

  for (int j = 1; j <= LK; ++j) {
    unsigned long long* Z = (j & 1) ? Z0 : Z1;
#pragma unroll
    for (int rr = 0; rr < 2; ++rr) {
      const int r = b * 16 + wave * 2 + rr;
      const float4* Mr = (const float4*)(Mlds + (wave * 2 + rr) * 2048);
      float s = 0.f;
#pragma unroll
      for (int t = 0; t < 8; ++t) {
        int idx = t * 64 + lane;
        float4 m4 = Mr[idx];
        float4 v4 = ((const float4*)Vcur)[idx];
        s += m4.x * v4.x + m4.y * v4.y + m4.z * v4.z + m4.w * v4.w;
      }
#pragma unroll
      for (int off = 32; off; off >>= 1) s += __shfl_down(s, off);
      if (lane == 0) {
        float zv = s - beta_prev * Vprev[r];
        unsigned long long pk = ((unsigned long long)(unsigned)j << 32) |
                                (unsigned long long)(unsigned)__float_as_uint(zv);
        __hip_atomic_store(&Z[r], pk, __ATOMIC_RELAXED, AGENT);
      }
    }

    // hoist own v-slice reads (LDS) ahead of the poll — free overlap
    float va[4];
#pragma unroll
    for (int t = 0; t < 4; ++t) va[t] = Vcur[t * 512 + tid];

    unsigned long long w4[4];
    int rounds = 0;
    for (;;) {
      bool ok = true;
#pragma unroll
      for (int t = 0; t < 4; ++t) {
        w4[t] = __hip_atomic_load(&Z[t * 512 + tid], __ATOMIC_RELAXED, AGENT);
        ok &= ((unsigned)(w4[t] >> 32) == (unsigned)j);
      }
      if (ok) break;
      if (rounds == 1)      __builtin_amdgcn_s_sleep(1);   //  64 clk
      else if (rounds == 2) __builtin_amdgcn_s_sleep(2);   // 128 clk
      else if (rounds >= 3) __builtin_amdgcn_s_sleep(8);   // 512 clk
      ++rounds;
    }
    float za[4];
    float pa = 0.f;
#pragma unroll
    for (int t = 0; t < 4; ++t) {
      za[t] = __uint_as_float((unsigned)w4[t]);
      pa += za[t] * va[t];
    }
    float alpha = block_sum8(pa, red);
    float pb = 0.f;
#pragma unroll
    for (int t = 0; t < 4; ++t) {
      float rsd = za[t] - alpha * va[t];
      pb += rsd * rsd;
    }
    float beta2 = block_sum8(pb, red);
    float beta = sqrtf(fmaxf(beta2, 1e-30f));
    float invb = 1.f / beta;
    if (tid == 0) { al[j] = alpha; b2[j] = beta2; }
#pragma unroll
    for (int t = 0; t < 4; ++t) {
      int i = t * 512 + tid;
      Vprev[i] = (za[t] - alpha * va[t]) * invb;
    }
    float* tmp = Vprev; Vprev = Vcur; Vcur = tmp;
    beta_prev = beta;
    __syncthreads();
  }

  // ---- extreme eigenvalues of T via Sturm bisection (block 0) ----
  if (b == 0) {
    if (tid == 0) {                                  // Gershgorin bounds on T
      float lo = 1e30f, hi = -1e30f;
      for (int i = 1; i <= LK; ++i) {
        float bl = (i > 1) ? sqrtf(b2[i - 1]) : 0.f;
        float br = (i < LK) ? sqrtf(b2[i]) : 0.f;
        lo = fminf(lo, al[i] - bl - br);
        hi = fmaxf(hi, al[i] + bl + br);
      }
      bnds[0] = lo; bnds[1] = hi;
    }
    __syncthreads();
    if (wave < 2) {                 // wave 0 -> lambda_min, wave 1 -> lambda_max
      const int tcount = (wave == 0) ? 1 : LK;
      float lo = bnds[0], hi = bnds[1];
      for (int round = 0; round < 4; ++round) {
        float x = lo + (hi - lo) * (float)(lane + 1) * (1.f / 65.f);
        int cnt = 0;                                 // #eigs of T below x
        float d = al[1] - x;
        if (fabsf(d) < 1e-25f) d = -1e-25f;
        if (d < 0.f) cnt++;
        for (int i = 2; i <= LK; ++i) {
          d = (al[i] - x) - b2[i - 1] / d;
          if (fabsf(d) < 1e-25f) d = -1e-25f;
          if (d < 0.f) cnt++;
        }
        bool ab = (cnt >= tcount);                   // x is above the target eig
        float cand_hi = ab ? x : hi;
        float cand_lo = ab ? lo : x;
#pragma unroll
        for (int off = 32; off; off >>= 1) {
          cand_hi = fminf(cand_hi, __shfl_down(cand_hi, off));
          cand_lo = fmaxf(cand_lo, __shfl_down(cand_lo, off));
        }
        cand_hi = __shfl(cand_hi, 0);
        cand_lo = __shfl(cand_lo, 0);
        hi = cand_hi;
        lo = fminf(cand_lo, hi);
      }
      if (lane == 0) res[wave] = 0.5f * (lo + hi);
    }
    __syncthreads();
    if (tid == 0) {
      float lmin = fmaxf(res[0], 1e-12f);
      float lmax = fmaxf(res[1], 1e-12f);
      out[0] = logf(lmax) - logf(lmin);
    }
  }
}

extern "C" void kernel_launch(void* const* d_in, const int* in_sizes, int n_in,
                              void* d_out, int out_size, void* d_ws, size_t ws_size,
                              hipStream_t stream) {
  const float* pred = (const float*)d_in[0];
  const float* scal = (const float*)d_in[1];
  const float* W    = (const float*)d_in[2];
  const int*   rows = (const int*)d_in[3];
  const int*   cols = (const int*)d_in[4];
  float* out = (float*)d_out;

  // workspace layout (peak ~41.1 MB):
  //  [0,8MB)   : Hf fp16 (dead after gemm) -> Ft fp16
  //  [8,16MB)  : A fp16
  //  [16,24MB) : F fp16
  //  [24,40MB) : M fp32
  //  [40MB,..) : cnt, fixed-stride bins, epoch-tagged Z ping-pong
  char* ws = (char*)d_ws;
  const size_t MB = 1024 * 1024;
  unsigned short* Hf = (unsigned short*)(ws);
  unsigned short* Ah = (unsigned short*)(ws + 8 * MB);
  unsigned short* F  = (unsigned short*)(ws + 16 * MB);
  unsigned short* Ft = (unsigned short*)(ws);          // reuses Hf (dead after gemm)
  float* M = (float*)(ws + 24 * MB);
  char* ctrl = ws + 40 * MB;
  unsigned* cnt  = (unsigned*)(ctrl);                    //  8 KB (zeroed by convert)
  int*      bcol = (int*)(ctrl + 8192);                  //  512 KB (2048 x 64)
  float*    bval = (float*)(ctrl + 8192 + 524288);       //  512 KB
  unsigned long long* Z0 = (unsigned long long*)(ctrl + 8192 + 1048576);         // 16 KB
  unsigned long long* Z1 = (unsigned long long*)(ctrl + 8192 + 1048576 + 16384); // 16 KB

  convert_kernel<<<4096, 256, 0, stream>>>(W, Hf, cnt);
  // GEMM (split-K, XCD-swizzled) + fused fill; writes A fp16
  gemm_f16_kernel<<<512, 512, 0, stream>>>(Hf, Ah, pred, scal, rows, cols, cnt, bcol, bval);

  gatherF_kernel<<<2048, 256, 0, stream>>>(cnt, bcol, bval, Ah, F);    // F = S*A (fp16)
  transpose_kernel<<<dim3(32, 32), 256, 0, stream>>>(F, Ft);           // Ft = F^T
  finalM_kernel<<<2048, 256, 0, stream>>>(cnt, bcol, bval, Ah, F, Ft, M); // M in ONE pass

  // plain launch — 128 blocks x 512 threads, 147KB LDS => 1 block/CU, all resident
  lanczos_kernel<<<NBL, 512, 0, stream>>>(M, Z0, Z1, out);
}

// Round 8
// 255.413 us; speedup vs baseline: 1.2228x; 1.0041x over previous
//
#include <hip/hip_runtime.h>

// Problem constants (fixed by the reference)
#define N2 2048
#define NNZ 32768
#define LK 22          // FROZEN: absmax 0.0234 of 0.037 threshold (3 of ~4.7 bf16 ulps)
#define NBL 128        // lanczos grid blocks: 128 x 512 thr; 147KB LDS -> 1 block/CU
#define BINCAP 64      // slots per row bin (Poisson(16) tail ~1e-15)

typedef __attribute__((ext_vector_type(8))) _Float16 half8;
typedef __attribute__((ext_vector_type(4))) float f32x4;

#define AGENT __HIP_MEMORY_SCOPE_AGENT
#define AS1C(p) ((const __attribute__((address_space(1))) unsigned int*)(p))
#define AS3(p)  ((__attribute__((address_space(3))) unsigned int*)(p))

__device__ __forceinline__ unsigned short f2h(float f) {
  _Float16 h = (_Float16)f;                   // fp16 RNE
  return *(unsigned short*)&h;
}
__device__ __forceinline__ float h2f(unsigned short u) {
  _Float16 h = *(_Float16*)&u;
  return (float)h;
}

// ---- 1. W (fp32) -> fp16  (+ zero cnt for the binning pass) ----
__global__ __launch_bounds__(256) void convert_kernel(const float* __restrict__ W,
                                                      unsigned short* __restrict__ Hf,
                                                      unsigned* __restrict__ cnt) {
  if (blockIdx.x < 8) cnt[blockIdx.x * 256 + threadIdx.x] = 0;
  int i4 = blockIdx.x * 256 + threadIdx.x;          // grid 4096 -> 1048576 float4s
  float4 w = ((const float4*)W)[i4];
  ushort4 h;
  h.x = f2h(w.x); h.y = f2h(w.y); h.z = f2h(w.z); h.w = f2h(w.w);
  ((ushort4*)Hf)[i4] = h;
}

// ---- 2. A = Hf*Hf^T/N + I — SYMMETRIC-HALF split-K GEMM (R23) ----
// A is symmetric by construction; compute only 272 of 512 tiles:
//   b < 32:   diagonal-band tiles (bi = 2bj, 2bj+1) — full direct write.
//   b >= 32:  pure-lower tiles (bi >= 2bj+2) — direct write + mirrored write
//             of the transposed tile into the upper triangle (values parked
//             in the Cred LDS buffer by the split-K combine, bitwise equal).
// Coverage: entry (i,j), i<j: same 128-col-band -> band tile; else mirror of
// pure-lower tile (j>>6, i>>7). Disjoint, complete. MFMA + panel reads 53%.
// Fused fill unchanged on blocks 0..63.
__global__ __launch_bounds__(512) void gemm_f16_kernel(const unsigned short* __restrict__ Hf,
                                                       unsigned short* __restrict__ Ah,
                                                       const float* __restrict__ pred,
                                                       const float* __restrict__ scal,
                                                       const int* __restrict__ rows,
                                                       const int* __restrict__ cols,
                                                       unsigned* __restrict__ cnt,
                                                       int* __restrict__ bcol,
                                                       float* __restrict__ bval) {
  const int tid = threadIdx.x;
  // ---- fused fill: 64 blocks x 512 threads cover NNZ=32768 ----
  if (blockIdx.x < 64) {
    int k = blockIdx.x * 512 + tid;
    int r = rows[k];
    unsigned pos = atomicAdd(&cnt[r], 1u);
    if (pos < BINCAP) {                     // Poisson(16) tail guard, ~never taken
      bcol[r * BINCAP + pos] = cols[k];
      bval[r * BINCAP + pos] = pred[k] * scal[k];
    }
  }

  // ---- tile mapping: 32 diag-band + 240 pure-lower ----
  int bi, bj;
  bool diag;
  if (blockIdx.x < 32) {
    bi = blockIdx.x; bj = bi >> 1; diag = true;
  } else {
    int idx = blockIdx.x - 32;                // 0..239
    int j = 0;                                 // off(j) = j*(31-j)
    while (j < 14 && idx >= (j + 1) * (30 - j)) ++j;
    bj = j;
    bi = 2 * j + 2 + (idx - j * (31 - j));
    diag = false;
  }

  __shared__ unsigned short Xs[2][64 * 32];
  __shared__ unsigned short Ys[2][128 * 32];
  __shared__ float Cred[64 * 132];          // pad 128->132: 2-way banks (free)
  const int w = tid >> 6, lane = tid & 63;
  const int half = w >> 2, wq = w & 3;      // k-half, role within half
  const int row0 = bi * 64, col0 = bj * 128;
  const int m0 = (wq & 1) * 32, n0 = (wq >> 1) * 64;
  f32x4 acc[2][4];
#pragma unroll
  for (int a = 0; a < 2; ++a)
#pragma unroll
    for (int b = 0; b < 4; ++b) acc[a][b] = (f32x4){0.f, 0.f, 0.f, 0.f};
  const int mrow = lane & 15, kseg = (lane >> 4) * 8;
  const int srowX = wq * 16 + (lane >> 2);          // Xs: 16 rows/wave
  const int srowY = wq * 32 + (lane >> 2);          // Ys: 32 rows/wave (2 issues)
  const int scol = (lane & 3) * 8;
  const int kbase = half * 1024;

  for (int k0 = 0; k0 < 1024; k0 += 32) {
    __syncthreads();
    __builtin_amdgcn_global_load_lds(
        AS1C(Hf + (size_t)(row0 + srowX) * 2048 + kbase + k0 + scol),
        AS3(Xs[half] + (wq * 16) * 32), 16, 0, 0);
#pragma unroll
    for (int q = 0; q < 2; ++q) {
      __builtin_amdgcn_global_load_lds(
          AS1C(Hf + (size_t)(col0 + srowY + q * 16) * 2048 + kbase + k0 + scol),
          AS3(Ys[half] + (wq * 32 + q * 16) * 32), 16, 0, 0);
    }
    __syncthreads();
    half8 af[2], bf[4];
#pragma unroll
    for (int t = 0; t < 2; ++t)
      af[t] = *(const half8*)(Xs[half] + (m0 + t * 16 + mrow) * 32 + kseg);
#pragma unroll
    for (int t = 0; t < 4; ++t)
      bf[t] = *(const half8*)(Ys[half] + (n0 + t * 16 + mrow) * 32 + kseg);
#pragma unroll
    for (int mt = 0; mt < 2; ++mt)
#pragma unroll
      for (int nt = 0; nt < 4; ++nt)
        acc[mt][nt] = __builtin_amdgcn_mfma_f32_16x16x32_f16(af[mt], bf[nt], acc[mt][nt], 0, 0, 0);
  }
  // ---- combine halves: high -> LDS, low adds and stores fp16 A ----
  // C/D layout: col = lane&15, row = (lane>>4)*4 + reg   [m89-verified]
  const int crow = (lane >> 4) * 4, ccol = lane & 15;
  __syncthreads();
  if (half == 1) {
#pragma unroll
    for (int mt = 0; mt < 2; ++mt)
#pragma unroll
      for (int nt = 0; nt < 4; ++nt)
#pragma unroll
        for (int r = 0; r < 4; ++r)
          Cred[(m0 + mt * 16 + crow + r) * 132 + n0 + nt * 16 + ccol] = acc[mt][nt][r];
  }
  __syncthreads();
  if (half == 0) {
    const float invn = 1.0f / 2048.0f;
#pragma unroll
    for (int mt = 0; mt < 2; ++mt)
#pragma unroll
      for (int nt = 0; nt < 4; ++nt) {
        const int gi0 = row0 + m0 + mt * 16 + crow;
        const int gj = col0 + n0 + nt * 16 + ccol;
        size_t base = (size_t)gi0 * 2048 + gj;
#pragma unroll
        for (int r = 0; r < 4; ++r) {
          const int li = (m0 + mt * 16 + crow + r) * 132 + n0 + nt * 16 + ccol;
          float val = (acc[mt][nt][r] + Cred[li]) * invn +
                      ((gi0 + r == gj) ? 1.0f : 0.0f);
          Ah[base + (size_t)r * 2048] = f2h(val);
          if (!diag) Cred[li] = val;        // park final value for mirror pass
        }
      }
  }
  if (!diag) {
    __syncthreads();                         // Cred now holds the final tile
    // mirrored write: upper-triangle image, rows [128bj..+128) x cols [64bi..+64)
    const int orow = tid >> 2;               // 0..127 (original tile col)
    const int cseg = (tid & 3) * 16;         // 0..48  (original tile row base)
    unsigned short mv[16];
#pragma unroll
    for (int k = 0; k < 16; ++k)
      mv[k] = f2h(Cred[(cseg + k) * 132 + orow]);
    uint4* dst = (uint4*)(Ah + (size_t)(col0 + orow) * 2048 + row0 + cseg);
    dst[0] = *(uint4*)&mv[0];
    dst[1] = *(uint4*)&mv[8];
  }
}

// ---- 4d. F[r,:] = sum_e val_e * A[col_e,:]  (fp16, fp32 accum) ----
// R22: bin metadata staged in LDS; 4-way unrolled row loads (MLP 1 -> 4).
__global__ __launch_bounds__(256) void gatherF_kernel(const unsigned* __restrict__ cnt,
                                                      const int* __restrict__ bcol,
                                                      const float* __restrict__ bval,
                                                      const unsigned short* __restrict__ Ah,
                                                      unsigned short* __restrict__ F) {
  const int r = blockIdx.x, tid = threadIdx.x;
  __shared__ int scol_[BINCAP];
  __shared__ float sval_[BINCAP];
  const unsigned ne = min(cnt[r], (unsigned)BINCAP);
  if (tid < ne) {
    scol_[tid] = bcol[r * BINCAP + tid];
    sval_[tid] = bval[r * BINCAP + tid];
  }
  __syncthreads();
  float acc[8] = {0.f, 0.f, 0.f, 0.f, 0.f, 0.f, 0.f, 0.f};
  unsigned e = 0;
  for (; e + 4 <= ne; e += 4) {
    uint4 q0 = *(const uint4*)(Ah + (size_t)scol_[e + 0] * 2048 + tid * 8);
    uint4 q1 = *(const uint4*)(Ah + (size_t)scol_[e + 1] * 2048 + tid * 8);
    uint4 q2 = *(const uint4*)(Ah + (size_t)scol_[e + 2] * 2048 + tid * 8);
    uint4 q3 = *(const uint4*)(Ah + (size_t)scol_[e + 3] * 2048 + tid * 8);
    half8 h0 = *(half8*)&q0, h1 = *(half8*)&q1, h2 = *(half8*)&q2, h3 = *(half8*)&q3;
    const float v0 = sval_[e], v1 = sval_[e + 1], v2 = sval_[e + 2], v3 = sval_[e + 3];
#pragma unroll
    for (int k = 0; k < 8; ++k) {
      acc[k] += v0 * (float)h0[k];
      acc[k] += v1 * (float)h1[k];
      acc[k] += v2 * (float)h2[k];
      acc[k] += v3 * (float)h3[k];
    }
  }
  for (; e < ne; ++e) {
    uint4 q = *(const uint4*)(Ah + (size_t)scol_[e] * 2048 + tid * 8);
    half8 hv = *(half8*)&q;
    const float v = sval_[e];
#pragma unroll
    for (int k = 0; k < 8; ++k) acc[k] += v * (float)hv[k];
  }
  unsigned short o[8];
#pragma unroll
  for (int k = 0; k < 8; ++k) o[k] = f2h(acc[k]);
  *(uint4*)(F + (size_t)r * 2048 + tid * 8) = *(uint4*)o;
}

// ---- 5a. Ft = F^T  (fp16, 64x64 tiles) ----
__global__ __launch_bounds__(256) void transpose_kernel(const unsigned short* __restrict__ F,
                                                        unsigned short* __restrict__ Ft) {
  __shared__ unsigned short T2[64][66];     // stride 132B: 4B-aligned, read-spread
  const int bi = blockIdx.x, bj = blockIdx.y;
  const int c8 = (threadIdx.x & 7) * 8;
  const int rr = threadIdx.x >> 3;
#pragma unroll
  for (int h = 0; h < 2; ++h) {
    const int r = rr + h * 32;
    uint4 raw = *(const uint4*)(F + (size_t)(bj * 64 + r) * 2048 + bi * 64 + c8);
    const unsigned* pw = (const unsigned*)&raw;
#pragma unroll
    for (int i = 0; i < 4; ++i)
      *(unsigned*)&T2[r][c8 + i * 2] = pw[i];
  }
  __syncthreads();
#pragma unroll
  for (int h = 0; h < 2; ++h) {
    const int r = rr + h * 32;
    unsigned short tv[8];
#pragma unroll
    for (int k = 0; k < 8; ++k) tv[k] = T2[c8 + k][r];
    *(uint4*)(Ft + (size_t)(bi * 64 + r) * 2048 + bj * 64 + c8) = *(uint4*)tv;
  }
}

// ---- 5b. finalM: M[r,:] = A + F + Ft + sum_e val_e*Ft[col_e,:]  (ONE M pass) ----
__global__ __launch_bounds__(256) void finalM_kernel(const unsigned* __restrict__ cnt,
                                                     const int* __restrict__ bcol,
                                                     const float* __restrict__ bval,
                                                     const unsigned short* __restrict__ Ah,
                                                     const unsigned short* __restrict__ F,
                                                     const unsigned short* __restrict__ Ft,
                                                     float* __restrict__ M) {
  const int r = blockIdx.x, tid = threadIdx.x;
  __shared__ int scol_[BINCAP];
  __shared__ float sval_[BINCAP];
  const unsigned ne = min(cnt[r], (unsigned)BINCAP);
  if (tid < ne) {
    scol_[tid] = bcol[r * BINCAP + tid];
    sval_[tid] = bval[r * BINCAP + tid];
  }
  __syncthreads();
  float acc[8] = {0.f, 0.f, 0.f, 0.f, 0.f, 0.f, 0.f, 0.f};
  unsigned e = 0;
  for (; e + 4 <= ne; e += 4) {
    uint4 q0 = *(const uint4*)(Ft + (size_t)scol_[e + 0] * 2048 + tid * 8);
    uint4 q1 = *(const uint4*)(Ft + (size_t)scol_[e + 1] * 2048 + tid * 8);
    uint4 q2 = *(const uint4*)(Ft + (size_t)scol_[e + 2] * 2048 + tid * 8);
    uint4 q3 = *(const uint4*)(Ft + (size_t)scol_[e + 3] * 2048 + tid * 8);
    half8 h0 = *(half8*)&q0, h1 = *(half8*)&q1, h2 = *(half8*)&q2, h3 = *(half8*)&q3;
    const float v0 = sval_[e], v1 = sval_[e + 1], v2 = sval_[e + 2], v3 = sval_[e + 3];
#pragma unroll
    for (int k = 0; k < 8; ++k) {
      acc[k] += v0 * (float)h0[k];
      acc[k] += v1 * (float)h1[k];
      acc[k] += v2 * (float)h2[k];
      acc[k] += v3 * (float)h3[k];
    }
  }
  for (; e < ne; ++e) {
    uint4 q = *(const uint4*)(Ft + (size_t)scol_[e] * 2048 + tid * 8);
    half8 hv = *(half8*)&q;
    const float v = sval_[e];
#pragma unroll
    for (int k = 0; k < 8; ++k) acc[k] += v * (float)hv[k];
  }
  // combine: M = A + F + Ft + acc   (single fp32 write pass)
  const size_t off = (size_t)r * 2048 + tid * 8;
  uint4 ra = *(const uint4*)(Ah + off);
  uint4 rf = *(const uint4*)(F + off);
  uint4 rt = *(const uint4*)(Ft + off);
  half8 ha = *(half8*)&ra, hf = *(half8*)&rf, ht = *(half8*)&rt;
  float out[8];
#pragma unroll
  for (int k = 0; k < 8; ++k)
    out[k] = (float)ha[k] + ((float)hf[k] + (float)ht[k]) + acc[k];
  float4* Mo = (float4*)(M + off);
  Mo[0] = (float4){out[0], out[1], out[2], out[3]};
  Mo[1] = (float4){out[4], out[5], out[6], out[7]};
}

// ---- deterministic block-wide sum over 8 waves: bitwise-identical per block ----
__device__ __forceinline__ float block_sum8(float v, float* red) {
#pragma unroll
  for (int off = 32; off; off >>= 1) v += __shfl_down(v, off);
  if ((threadIdx.x & 63) == 0) red[threadIdx.x >> 6] = v;
  __syncthreads();
  float r = ((red[0] + red[1]) + (red[2] + red[3])) +
            ((red[4] + red[5]) + (red[6] + red[7]));
  __syncthreads();
  return r;
}

// ---- 6. Lanczos: single-phase epoch protocol, 128 x 512 — FROZEN (R20) ----
// R20: ~4.2 us/iter exchange is the store->remote-observability floor of an
// agent-scope publish under polling — robust to protocol shape (R0/R1/R3),
// traffic volume (R3 backoff), and agent count (R4). Do not retune.
// RULE 1 (R1/R6): cross-block data via agent-scope atomics only.
// RULE 2 (R1/R6/R8): beta^2 = ||z - alpha v||^2 DIRECT form only.
// RULE 3 (R16): no fixed-address staging reuse with plain cached loads.
// RULE 4 (R17): exactly ONE publish->consume phase per iteration.
// RULE 5 (R19/R20): exchange cost is per-phase visibility latency.
__global__ __launch_bounds__(512) void lanczos_kernel(const float* __restrict__ M,
                                                      unsigned long long* __restrict__ Z0,
                                                      unsigned long long* __restrict__ Z1,
                                                      float* __restrict__ out) {
  const int tid = threadIdx.x, b = blockIdx.x;
  const int wave = tid >> 6, lane = tid & 63;
  __shared__ __align__(16) float Mlds[16 * 2048];  // 128 KB: this block's 16 rows
  __shared__ __align__(16) float VA[2048];
  __shared__ __align__(16) float VB[2048];
  __shared__ float red[8];
  __shared__ float al[LK + 2], b2[LK + 2];
  __shared__ float bnds[2], res[2];

  const float* Mblk = M + (size_t)b * 16 * 2048;
#pragma unroll
  for (int q = 0; q < 16; ++q)
    __builtin_amdgcn_global_load_lds(AS1C(Mblk + wave * 4096 + q * 256 + lane * 4),
                                     AS3(Mlds + wave * 4096 + q * 256), 16, 0, 0);

  // block-redundant init: v1 = hash / ||hash||  (identical in every block), v0 = 0
  float pv[4];
  float part = 0.f;
#pragma unroll
  for (int t = 0; t < 4; ++t) {
    int i = t * 512 + tid;
    unsigned u = (unsigned)i * 2654435761u;
    u ^= u >> 16; u *= 2246822519u; u ^= u >> 13;
    float rv = (float)(u >> 8) * (2.f / 16777216.f) - 1.f;
    pv[t] = rv;
    part += rv * rv;
  }
  float nrm = block_sum8(part, red);
  float innm = rsqrtf(nrm);
#pragma unroll
  for (int t = 0; t < 4; ++t) {
    int i = t * 512 + tid;
    VA[i] = pv[t] * innm;
    VB[i] = 0.f;
  }
  __syncthreads();

  float* Vcur = VA;
  float* Vprev = VB;
  float beta_prev = 0.f;

  for (int j = 1; j <= LK; ++j) {
    unsigned long long* Z = (j & 1) ? Z0 : Z1;
#pragma unroll
    for (int rr = 0; rr < 2; ++rr) {
      const int r = b * 16 + wave * 2 + rr;
      const float4* Mr = (const float4*)(Mlds + (wave * 2 + rr) * 2048);
      float s = 0.f;
#pragma unroll
      for (int t = 0; t < 8; ++t) {
        int idx = t * 64 + lane;
        float4 m4 = Mr[idx];
        float4 v4 = ((const float4*)Vcur)[idx];
        s += m4.x * v4.x + m4.y * v4.y + m4.z * v4.z + m4.w * v4.w;
      }
#pragma unroll
      for (int off = 32; off; off >>= 1) s += __shfl_down(s, off);
      if (lane == 0) {
        float zv = s - beta_prev * Vprev[r];
        unsigned long long pk = ((unsigned long long)(unsigned)j << 32) |
                                (unsigned long long)(unsigned)__float_as_uint(zv);
        __hip_atomic_store(&Z[r], pk, __ATOMIC_RELAXED, AGENT);
      }
    }

    // hoist own v-slice reads (LDS) ahead of the poll — free overlap
    float va[4];
#pragma unroll
    for (int t = 0; t < 4; ++t) va[t] = Vcur[t * 512 + tid];

    unsigned long long w4[4];
    int rounds = 0;
    for (;;) {
      bool ok = true;
#pragma unroll
      for (int t = 0; t < 4; ++t) {
        w4[t] = __hip_atomic_load(&Z[t * 512 + tid], __ATOMIC_RELAXED, AGENT);
        ok &= ((unsigned)(w4[t] >> 32) == (unsigned)j);
      }
      if (ok) break;
      if (rounds == 1)      __builtin_amdgcn_s_sleep(1);   //  64 clk
      else if (rounds == 2) __builtin_amdgcn_s_sleep(2);   // 128 clk
      else if (rounds >= 3) __builtin_amdgcn_s_sleep(8);   // 512 clk
      ++rounds;
    }
    float za[4];
    float pa = 0.f;
#pragma unroll
    for (int t = 0; t < 4; ++t) {
      za[t] = __uint_as_float((unsigned)w4[t]);
      pa += za[t] * va[t];
    }
    float alpha = block_sum8(pa, red);
    float pb = 0.f;
#pragma unroll
    for (int t = 0; t < 4; ++t) {
      float rsd = za[t] - alpha * va[t];
      pb += rsd * rsd;
    }
    float beta2 = block_sum8(pb, red);
    float beta = sqrtf(fmaxf(beta2, 1e-30f));
    float invb = 1.f / beta;
    if (tid == 0) { al[j] = alpha; b2[j] = beta2; }
#pragma unroll
    for (int t = 0; t < 4; ++t) {
      int i = t * 512 + tid;
      Vprev[i] = (za[t] - alpha * va[t]) * invb;
    }
    float* tmp = Vprev; Vprev = Vcur; Vcur = tmp;
    beta_prev = beta;
    __syncthreads();
  }

  // ---- extreme eigenvalues of T via Sturm bisection (block 0) ----
  if (b == 0) {
    if (tid == 0) {                                  // Gershgorin bounds on T
      float lo = 1e30f, hi = -1e30f;
      for (int i = 1; i <= LK; ++i) {
        float bl = (i > 1) ? sqrtf(b2[i - 1]) : 0.f;
        float br = (i < LK) ? sqrtf(b2[i]) : 0.f;
        lo = fminf(lo, al[i] - bl - br);
        hi = fmaxf(hi, al[i] + bl + br);
      }
      bnds[0] = lo; bnds[1] = hi;
    }
    __syncthreads();
    if (wave < 2) {                 // wave 0 -> lambda_min, wave 1 -> lambda_max
      const int tcount = (wave == 0) ? 1 : LK;
      float lo = bnds[0], hi = bnds[1];
      for (int round = 0; round < 4; ++round) {
        float x = lo + (hi - lo) * (float)(lane + 1) * (1.f / 65.f);
        int cnt = 0;                                 // #eigs of T below x
        float d = al[1] - x;
        if (fabsf(d) < 1e-25f) d = -1e-25f;
        if (d < 0.f) cnt++;
        for (int i = 2; i <= LK; ++i) {
          d = (al[i] - x) - b2[i - 1] / d;
          if (fabsf(d) < 1e-25f) d = -1e-25f;
          if (d < 0.f) cnt++;
        }
        bool ab = (cnt >= tcount);                   // x is above the target eig
        float cand_hi = ab ? x : hi;
        float cand_lo = ab ? lo : x;
#pragma unroll
        for (int off = 32; off; off >>= 1) {
          cand_hi = fminf(cand_hi, __shfl_down(cand_hi, off));
          cand_lo = fmaxf(cand_lo, __shfl_down(cand_lo, off));
        }
        cand_hi = __shfl(cand_hi, 0);
        cand_lo = __shfl(cand_lo, 0);
        hi = cand_hi;
        lo = fminf(cand_lo, hi);
      }
      if (lane == 0) res[wave] = 0.5f * (lo + hi);
    }
    __syncthreads();
    if (tid == 0) {
      float lmin = fmaxf(res[0], 1e-12f);
      float lmax = fmaxf(res[1], 1e-12f);
      out[0] = logf(lmax) - logf(lmin);
    }
  }
}

extern "C" void kernel_launch(void* const* d_in, const int* in_sizes, int n_in,
                              void* d_out, int out_size, void* d_ws, size_t ws_size,
                              hipStream_t stream) {
  const float* pred = (const float*)d_in[0];
  const float* scal = (const float*)d_in[1];
  const float* W    = (const float*)d_in[2];
  const int*   rows = (const int*)d_in[3];
  const int*   cols = (const int*)d_in[4];
  float* out = (float*)d_out;

  // workspace layout (peak ~41.1 MB):
  //  [0,8MB)   : Hf fp16 (dead after gemm) -> Ft fp16
  //  [8,16MB)  : A fp16
  //  [16,24MB) : F fp16
  //  [24,40MB) : M fp32
  //  [40MB,..) : cnt, fixed-stride bins, epoch-tagged Z ping-pong
  char* ws = (char*)d_ws;
  const size_t MB = 1024 * 1024;
  unsigned short* Hf = (unsigned short*)(ws);
  unsigned short* Ah = (unsigned short*)(ws + 8 * MB);
  unsigned short* F  = (unsigned short*)(ws + 16 * MB);
  unsigned short* Ft = (unsigned short*)(ws);          // reuses Hf (dead after gemm)
  float* M = (float*)(ws + 24 * MB);
  char* ctrl = ws + 40 * MB;
  unsigned* cnt  = (unsigned*)(ctrl);                    //  8 KB (zeroed by convert)
  int*      bcol = (int*)(ctrl + 8192);                  //  512 KB (2048 x 64)
  float*    bval = (float*)(ctrl + 8192 + 524288);       //  512 KB
  unsigned long long* Z0 = (unsigned long long*)(ctrl + 8192 + 1048576);         // 16 KB
  unsigned long long* Z1 = (unsigned long long*)(ctrl + 8192 + 1048576 + 16384); // 16 KB

  convert_kernel<<<4096, 256, 0, stream>>>(W, Hf, cnt);
  // symmetric-half GEMM (272 tiles: 32 diag-band full + 240 lower w/ mirror)
  gemm_f16_kernel<<<272, 512, 0, stream>>>(Hf, Ah, pred, scal, rows, cols, cnt, bcol, bval);

  gatherF_kernel<<<2048, 256, 0, stream>>>(cnt, bcol, bval, Ah, F);    // F = S*A (fp16)
  transpose_kernel<<<dim3(32, 32), 256, 0, stream>>>(F, Ft);           // Ft = F^T
  finalM_kernel<<<2048, 256, 0, stream>>>(cnt, bcol, bval, Ah, F, Ft, M); // M in ONE pass

  // plain launch — 128 blocks x 512 threads, 147KB LDS => 1 block/CU, all resident
  lanczos_kernel<<<NBL, 512, 0, stream>>>(M, Z0, Z1, out);
}

// Round 9
// 251.176 us; speedup vs baseline: 1.2434x; 1.0169x over previous
//
#include <hip/hip_runtime.h>

// Problem constants (fixed by the reference)
#define N2 2048
#define NNZ 32768
#define LK 22          // FROZEN: absmax 0.0234 of 0.037 threshold (3 of ~4.7 bf16 ulps)
#define NBL 128        // lanczos grid blocks: 128 x 512 thr; 147KB LDS -> 1 block/CU
#define BINCAP 64      // slots per row bin (Poisson(16) tail ~1e-15)

typedef __attribute__((ext_vector_type(8))) _Float16 half8;
typedef __attribute__((ext_vector_type(4))) float f32x4;

#define AGENT __HIP_MEMORY_SCOPE_AGENT
#define AS1C(p) ((const __attribute__((address_space(1))) unsigned int*)(p))
#define AS3(p)  ((__attribute__((address_space(3))) unsigned int*)(p))

__device__ __forceinline__ unsigned short f2h(float f) {
  _Float16 h = (_Float16)f;                   // fp16 RNE
  return *(unsigned short*)&h;
}
__device__ __forceinline__ float h2f(unsigned short u) {
  _Float16 h = *(_Float16*)&u;
  return (float)h;
}

// ---- 1. W (fp32) -> fp16  (+ zero cnt for the binning pass) ----
__global__ __launch_bounds__(256) void convert_kernel(const float* __restrict__ W,
                                                      unsigned short* __restrict__ Hf,
                                                      unsigned* __restrict__ cnt) {
  if (blockIdx.x < 8) cnt[blockIdx.x * 256 + threadIdx.x] = 0;
  int i4 = blockIdx.x * 256 + threadIdx.x;          // grid 4096 -> 1048576 float4s
  float4 w = ((const float4*)W)[i4];
  ushort4 h;
  h.x = f2h(w.x); h.y = f2h(w.y); h.z = f2h(w.z); h.w = f2h(w.w);
  ((ushort4*)Hf)[i4] = h;
}

// ---- 2. A = Hf*Hf^T/N + I — symmetric-half split-K GEMM, DOUBLE-BUFFERED (R24)
// R24 post-mortem of R5/R8 nulls: all blocks are co-resident, so GEMM wall =
// per-block critical path. Old loop serialized load-latency + compute every
// k-step (barrier right after issuing loads). Now: prologue-stage tile 0;
// per iteration {barrier; stage tile t+1 into other buffer; compute tile t}
// -> load latency hides under MFMA+ds_read, ONE barrier per k-step.
// Cred (33KB, post-loop only) ALIASES the staging buffers: LDS 48KB -> 3
// blocks/CU, 272 blocks still a single scheduling round.
// Symmetric-half tiling (R23) and fused fill (R20) unchanged.
__device__ __forceinline__ void stage_tiles(const unsigned short* __restrict__ Hf,
                                            unsigned short* Xb, unsigned short* Yb,
                                            int row0, int col0, int kk,
                                            int srowX, int srowY, int scol, int wq) {
  __builtin_amdgcn_global_load_lds(
      AS1C(Hf + (size_t)(row0 + srowX) * 2048 + kk + scol),
      AS3(Xb + (wq * 16) * 32), 16, 0, 0);
#pragma unroll
  for (int q = 0; q < 2; ++q) {
    __builtin_amdgcn_global_load_lds(
        AS1C(Hf + (size_t)(col0 + srowY + q * 16) * 2048 + kk + scol),
        AS3(Yb + (wq * 32 + q * 16) * 32), 16, 0, 0);
  }
}

__global__ __launch_bounds__(512) void gemm_f16_kernel(const unsigned short* __restrict__ Hf,
                                                       unsigned short* __restrict__ Ah,
                                                       const float* __restrict__ pred,
                                                       const float* __restrict__ scal,
                                                       const int* __restrict__ rows,
                                                       const int* __restrict__ cols,
                                                       unsigned* __restrict__ cnt,
                                                       int* __restrict__ bcol,
                                                       float* __restrict__ bval) {
  const int tid = threadIdx.x;
  // ---- fused fill: 64 blocks x 512 threads cover NNZ=32768 ----
  if (blockIdx.x < 64) {
    int k = blockIdx.x * 512 + tid;
    int r = rows[k];
    unsigned pos = atomicAdd(&cnt[r], 1u);
    if (pos < BINCAP) {                     // Poisson(16) tail guard, ~never taken
      bcol[r * BINCAP + pos] = cols[k];
      bval[r * BINCAP + pos] = pred[k] * scal[k];
    }
  }

  // ---- tile mapping: 32 diag-band + 240 pure-lower (R23) ----
  int bi, bj;
  bool diag;
  if (blockIdx.x < 32) {
    bi = blockIdx.x; bj = bi >> 1; diag = true;
  } else {
    int idx = blockIdx.x - 32;                // 0..239
    int j = 0;                                 // off(j) = j*(31-j)
    while (j < 14 && idx >= (j + 1) * (30 - j)) ++j;
    bj = j;
    bi = 2 * j + 2 + (idx - j * (31 - j));
    diag = false;
  }

  // LDS: staging (48KB: Xs 2half x 2buf x 64x32, Ys 2half x 2buf x 128x32),
  // Cred aliases the same memory after the k-loop (33KB < 48KB).
  __shared__ __align__(16) char smem[49152];
  unsigned short* Xs = (unsigned short*)smem;             // [half][buf][64*32]
  unsigned short* Ys = (unsigned short*)(smem + 16384);   // [half][buf][128*32]
  float* Cred = (float*)smem;                             // [64*132] post-loop

  const int w = tid >> 6, lane = tid & 63;
  const int half = w >> 2, wq = w & 3;      // k-half, role within half
  const int row0 = bi * 64, col0 = bj * 128;
  const int m0 = (wq & 1) * 32, n0 = (wq >> 1) * 64;
  f32x4 acc[2][4];
#pragma unroll
  for (int a = 0; a < 2; ++a)
#pragma unroll
    for (int b = 0; b < 4; ++b) acc[a][b] = (f32x4){0.f, 0.f, 0.f, 0.f};
  const int mrow = lane & 15, kseg = (lane >> 4) * 8;
  const int srowX = wq * 16 + (lane >> 2);          // Xs: 16 rows/wave
  const int srowY = wq * 32 + (lane >> 2);          // Ys: 32 rows/wave (2 issues)
  const int scol = (lane & 3) * 8;
  const int kbase = half * 1024;

  // prologue: stage k-tile 0 into buffer 0
  stage_tiles(Hf, Xs + (half * 2 + 0) * 2048, Ys + (half * 2 + 0) * 4096,
              row0, col0, kbase, srowX, srowY, scol, wq);

  for (int t = 0; t < 32; ++t) {
    const int cur = t & 1;
    __syncthreads();                        // buf[cur] loads complete grid-wide
    if (t < 31)                             // stage t+1 into the other buffer
      stage_tiles(Hf, Xs + (half * 2 + (cur ^ 1)) * 2048,
                  Ys + (half * 2 + (cur ^ 1)) * 4096,
                  row0, col0, kbase + (t + 1) * 32, srowX, srowY, scol, wq);
    const unsigned short* Xb = Xs + (half * 2 + cur) * 2048;
    const unsigned short* Yb = Ys + (half * 2 + cur) * 4096;
    half8 af[2], bf[4];
#pragma unroll
    for (int q = 0; q < 2; ++q)
      af[q] = *(const half8*)(Xb + (m0 + q * 16 + mrow) * 32 + kseg);
#pragma unroll
    for (int q = 0; q < 4; ++q)
      bf[q] = *(const half8*)(Yb + (n0 + q * 16 + mrow) * 32 + kseg);
#pragma unroll
    for (int mt = 0; mt < 2; ++mt)
#pragma unroll
      for (int nt = 0; nt < 4; ++nt)
        acc[mt][nt] = __builtin_amdgcn_mfma_f32_16x16x32_f16(af[mt], bf[nt], acc[mt][nt], 0, 0, 0);
  }
  // ---- combine halves (Cred aliases staging; barrier drains all LDS use) ----
  // C/D layout: col = lane&15, row = (lane>>4)*4 + reg   [m89-verified]
  const int crow = (lane >> 4) * 4, ccol = lane & 15;
  __syncthreads();
  if (half == 1) {
#pragma unroll
    for (int mt = 0; mt < 2; ++mt)
#pragma unroll
      for (int nt = 0; nt < 4; ++nt)
#pragma unroll
        for (int r = 0; r < 4; ++r)
          Cred[(m0 + mt * 16 + crow + r) * 132 + n0 + nt * 16 + ccol] = acc[mt][nt][r];
  }
  __syncthreads();
  if (half == 0) {
    const float invn = 1.0f / 2048.0f;
#pragma unroll
    for (int mt = 0; mt < 2; ++mt)
#pragma unroll
      for (int nt = 0; nt < 4; ++nt) {
        const int gi0 = row0 + m0 + mt * 16 + crow;
        const int gj = col0 + n0 + nt * 16 + ccol;
        size_t base = (size_t)gi0 * 2048 + gj;
#pragma unroll
        for (int r = 0; r < 4; ++r) {
          const int li = (m0 + mt * 16 + crow + r) * 132 + n0 + nt * 16 + ccol;
          float val = (acc[mt][nt][r] + Cred[li]) * invn +
                      ((gi0 + r == gj) ? 1.0f : 0.0f);
          Ah[base + (size_t)r * 2048] = f2h(val);
          if (!diag) Cred[li] = val;        // park final value for mirror pass
        }
      }
  }
  if (!diag) {
    __syncthreads();                         // Cred now holds the final tile
    // mirrored write: upper-triangle image, rows [128bj..+128) x cols [64bi..+64)
    const int orow = tid >> 2;               // 0..127 (original tile col)
    const int cseg = (tid & 3) * 16;         // 0..48  (original tile row base)
    unsigned short mv[16];
#pragma unroll
    for (int k = 0; k < 16; ++k)
      mv[k] = f2h(Cred[(cseg + k) * 132 + orow]);
    uint4* dst = (uint4*)(Ah + (size_t)(col0 + orow) * 2048 + row0 + cseg);
    dst[0] = *(uint4*)&mv[0];
    dst[1] = *(uint4*)&mv[8];
  }
}

// ---- 4d. F[r,:] = sum_e val_e * A[col_e,:]  (fp16, fp32 accum, MLP-8) ----
__global__ __launch_bounds__(256) void gatherF_kernel(const unsigned* __restrict__ cnt,
                                                      const int* __restrict__ bcol,
                                                      const float* __restrict__ bval,
                                                      const unsigned short* __restrict__ Ah,
                                                      unsigned short* __restrict__ F) {
  const int r = blockIdx.x, tid = threadIdx.x;
  __shared__ int scol_[BINCAP];
  __shared__ float sval_[BINCAP];
  const unsigned ne = min(cnt[r], (unsigned)BINCAP);
  if (tid < ne) {
    scol_[tid] = bcol[r * BINCAP + tid];
    sval_[tid] = bval[r * BINCAP + tid];
  }
  __syncthreads();
  float acc[8] = {0.f, 0.f, 0.f, 0.f, 0.f, 0.f, 0.f, 0.f};
  unsigned e = 0;
  for (; e + 8 <= ne; e += 8) {
    uint4 q[8];
#pragma unroll
    for (int u = 0; u < 8; ++u)
      q[u] = *(const uint4*)(Ah + (size_t)scol_[e + u] * 2048 + tid * 8);
#pragma unroll
    for (int u = 0; u < 8; ++u) {
      half8 hv = *(half8*)&q[u];
      const float v = sval_[e + u];
#pragma unroll
      for (int k = 0; k < 8; ++k) acc[k] += v * (float)hv[k];
    }
  }
  for (; e + 4 <= ne; e += 4) {
    uint4 q[4];
#pragma unroll
    for (int u = 0; u < 4; ++u)
      q[u] = *(const uint4*)(Ah + (size_t)scol_[e + u] * 2048 + tid * 8);
#pragma unroll
    for (int u = 0; u < 4; ++u) {
      half8 hv = *(half8*)&q[u];
      const float v = sval_[e + u];
#pragma unroll
      for (int k = 0; k < 8; ++k) acc[k] += v * (float)hv[k];
    }
  }
  for (; e < ne; ++e) {
    uint4 qq = *(const uint4*)(Ah + (size_t)scol_[e] * 2048 + tid * 8);
    half8 hv = *(half8*)&qq;
    const float v = sval_[e];
#pragma unroll
    for (int k = 0; k < 8; ++k) acc[k] += v * (float)hv[k];
  }
  unsigned short o[8];
#pragma unroll
  for (int k = 0; k < 8; ++k) o[k] = f2h(acc[k]);
  *(uint4*)(F + (size_t)r * 2048 + tid * 8) = *(uint4*)o;
}

// ---- 5a. Ft = F^T  (fp16, 64x64 tiles) ----
__global__ __launch_bounds__(256) void transpose_kernel(const unsigned short* __restrict__ F,
                                                        unsigned short* __restrict__ Ft) {
  __shared__ unsigned short T2[64][66];     // stride 132B: 4B-aligned, read-spread
  const int bi = blockIdx.x, bj = blockIdx.y;
  const int c8 = (threadIdx.x & 7) * 8;
  const int rr = threadIdx.x >> 3;
#pragma unroll
  for (int h = 0; h < 2; ++h) {
    const int r = rr + h * 32;
    uint4 raw = *(const uint4*)(F + (size_t)(bj * 64 + r) * 2048 + bi * 64 + c8);
    const unsigned* pw = (const unsigned*)&raw;
#pragma unroll
    for (int i = 0; i < 4; ++i)
      *(unsigned*)&T2[r][c8 + i * 2] = pw[i];
  }
  __syncthreads();
#pragma unroll
  for (int h = 0; h < 2; ++h) {
    const int r = rr + h * 32;
    unsigned short tv[8];
#pragma unroll
    for (int k = 0; k < 8; ++k) tv[k] = T2[c8 + k][r];
    *(uint4*)(Ft + (size_t)(bi * 64 + r) * 2048 + bj * 64 + c8) = *(uint4*)tv;
  }
}

// ---- 5b. finalM: M[r,:] = A + F + Ft + sum_e val_e*Ft[col_e,:]  (MLP-8) ----
__global__ __launch_bounds__(256) void finalM_kernel(const unsigned* __restrict__ cnt,
                                                     const int* __restrict__ bcol,
                                                     const float* __restrict__ bval,
                                                     const unsigned short* __restrict__ Ah,
                                                     const unsigned short* __restrict__ F,
                                                     const unsigned short* __restrict__ Ft,
                                                     float* __restrict__ M) {
  const int r = blockIdx.x, tid = threadIdx.x;
  __shared__ int scol_[BINCAP];
  __shared__ float sval_[BINCAP];
  const unsigned ne = min(cnt[r], (unsigned)BINCAP);
  if (tid < ne) {
    scol_[tid] = bcol[r * BINCAP + tid];
    sval_[tid] = bval[r * BINCAP + tid];
  }
  __syncthreads();
  float acc[8] = {0.f, 0.f, 0.f, 0.f, 0.f, 0.f, 0.f, 0.f};
  unsigned e = 0;
  for (; e + 8 <= ne; e += 8) {
    uint4 q[8];
#pragma unroll
    for (int u = 0; u < 8; ++u)
      q[u] = *(const uint4*)(Ft + (size_t)scol_[e + u] * 2048 + tid * 8);
#pragma unroll
    for (int u = 0; u < 8; ++u) {
      half8 hv = *(half8*)&q[u];
      const float v = sval_[e + u];
#pragma unroll
      for (int k = 0; k < 8; ++k) acc[k] += v * (float)hv[k];
    }
  }
  for (; e + 4 <= ne; e += 4) {
    uint4 q[4];
#pragma unroll
    for (int u = 0; u < 4; ++u)
      q[u] = *(const uint4*)(Ft + (size_t)scol_[e + u] * 2048 + tid * 8);
#pragma unroll
    for (int u = 0; u < 4; ++u) {
      half8 hv = *(half8*)&q[u];
      const float v = sval_[e + u];
#pragma unroll
      for (int k = 0; k < 8; ++k) acc[k] += v * (float)hv[k];
    }
  }
  for (; e < ne; ++e) {
    uint4 qq = *(const uint4*)(Ft + (size_t)scol_[e] * 2048 + tid * 8);
    half8 hv = *(half8*)&qq;
    const float v = sval_[e];
#pragma unroll
    for (int k = 0; k < 8; ++k) acc[k] += v * (float)hv[k];
  }
  // combine: M = A + F + Ft + acc   (single fp32 write pass)
  const size_t off = (size_t)r * 2048 + tid * 8;
  uint4 ra = *(const uint4*)(Ah + off);
  uint4 rf = *(const uint4*)(F + off);
  uint4 rt = *(const uint4*)(Ft + off);
  half8 ha = *(half8*)&ra, hf = *(half8*)&rf, ht = *(half8*)&rt;
  float out[8];
#pragma unroll
  for (int k = 0; k < 8; ++k)
    out[k] = (float)ha[k] + ((float)hf[k] + (float)ht[k]) + acc[k];
  float4* Mo = (float4*)(M + off);
  Mo[0] = (float4){out[0], out[1], out[2], out[3]};
  Mo[1] = (float4){out[4], out[5], out[6], out[7]};
}

// ---- deterministic block-wide sum over 8 waves: bitwise-identical per block ----
__device__ __forceinline__ float block_sum8(float v, float* red) {
#pragma unroll
  for (int off = 32; off; off >>= 1) v += __shfl_down(v, off);
  if ((threadIdx.x & 63) == 0) red[threadIdx.x >> 6] = v;
  __syncthreads();
  float r = ((red[0] + red[1]) + (red[2] + red[3])) +
            ((red[4] + red[5]) + (red[6] + red[7]));
  __syncthreads();
  return r;
}

// ---- 6. Lanczos: single-phase epoch protocol, 128 x 512 — FROZEN (R20) ----
// R20: ~4.2 us/iter exchange is the store->remote-observability floor of an
// agent-scope publish under polling — robust to protocol shape (R0/R1/R3),
// traffic volume (R3 backoff), and agent count (R4). Do not retune.
// RULE 1 (R1/R6): cross-block data via agent-scope atomics only.
// RULE 2 (R1/R6/R8): beta^2 = ||z - alpha v||^2 DIRECT form only.
// RULE 3 (R16): no fixed-address staging reuse with plain cached loads.
// RULE 4 (R17): exactly ONE publish->consume phase per iteration.
// RULE 5 (R19/R20): exchange cost is per-phase visibility latency.
__global__ __launch_bounds__(512) void lanczos_kernel(const float* __restrict__ M,
                                                      unsigned long long* __restrict__ Z0,
                                                      unsigned long long* __restrict__ Z1,
                                                      float* __restrict__ out) {
  const int tid = threadIdx.x, b = blockIdx.x;
  const int wave = tid >> 6, lane = tid & 63;
  __shared__ __align__(16) float Mlds[16 * 2048];  // 128 KB: this block's 16 rows
  __shared__ __align__(16) float VA[2048];
  __shared__ __align__(16) float VB[2048];
  __shared__ float red[8];
  __shared__ float al[LK + 2], b2[LK + 2];
  __shared__ float bnds[2], res[2];

  const float* Mblk = M + (size_t)b * 16 * 2048;
#pragma unroll
  for (int q = 0; q < 16; ++q)
    __builtin_amdgcn_global_load_lds(AS1C(Mblk + wave * 4096 + q * 256 + lane * 4),
                                     AS3(Mlds + wave * 4096 + q * 256), 16, 0, 0);

  // block-redundant init: v1 = hash / ||hash||  (identical in every block), v0 = 0
  float pv[4];
  float part = 0.f;
#pragma unroll
  for (int t = 0; t < 4; ++t) {
    int i = t * 512 + tid;
    unsigned u = (unsigned)i * 2654435761u;
    u ^= u >> 16; u *= 2246822519u; u ^= u >> 13;
    float rv = (float)(u >> 8) * (2.f / 16777216.f) - 1.f;
    pv[t] = rv;
    part += rv * rv;
  }
  float nrm = block_sum8(part, red);
  float innm = rsqrtf(nrm);
#pragma unroll
  for (int t = 0; t < 4; ++t) {
    int i = t * 512 + tid;
    VA[i] = pv[t] * innm;
    VB[i] = 0.f;
  }
  __syncthreads();

  float* Vcur = VA;
  float* Vprev = VB;
  float beta_prev = 0.f;

  for (int j = 1; j <= LK; ++j) {
    unsigned long long* Z = (j & 1) ? Z0 : Z1;
#pragma unroll
    for (int rr = 0; rr < 2; ++rr) {
      const int r = b * 16 + wave * 2 + rr;
      const float4* Mr = (const float4*)(Mlds + (wave * 2 + rr) * 2048);
      float s = 0.f;
#pragma unroll
      for (int t = 0; t < 8; ++t) {
        int idx = t * 64 + lane;
        float4 m4 = Mr[idx];
        float4 v4 = ((const float4*)Vcur)[idx];
        s += m4.x * v4.x + m4.y * v4.y + m4.z * v4.z + m4.w * v4.w;
      }
#pragma unroll
      for (int off = 32; off; off >>= 1) s += __shfl_down(s, off);
      if (lane == 0) {
        float zv = s - beta_prev * Vprev[r];
        unsigned long long pk = ((unsigned long long)(unsigned)j << 32) |
                                (unsigned long long)(unsigned)__float_as_uint(zv);
        __hip_atomic_store(&Z[r], pk, __ATOMIC_RELAXED, AGENT);
      }
    }

    // hoist own v-slice reads (LDS) ahead of the poll — free overlap
    float va[4];
#pragma unroll
    for (int t = 0; t < 4; ++t) va[t] = Vcur[t * 512 + tid];

    unsigned long long w4[4];
    int rounds = 0;
    for (;;) {
      bool ok = true;
#pragma unroll
      for (int t = 0; t < 4; ++t) {
        w4[t] = __hip_atomic_load(&Z[t * 512 + tid], __ATOMIC_RELAXED, AGENT);
        ok &= ((unsigned)(w4[t] >> 32) == (unsigned)j);
      }
      if (ok) break;
      if (rounds == 1)      __builtin_amdgcn_s_sleep(1);   //  64 clk
      else if (rounds == 2) __builtin_amdgcn_s_sleep(2);   // 128 clk
      else if (rounds >= 3) __builtin_amdgcn_s_sleep(8);   // 512 clk
      ++rounds;
    }
    float za[4];
    float pa = 0.f;
#pragma unroll
    for (int t = 0; t < 4; ++t) {
      za[t] = __uint_as_float((unsigned)w4[t]);
      pa += za[t] * va[t];
    }
    float alpha = block_sum8(pa, red);
    float pb = 0.f;
#pragma unroll
    for (int t = 0; t < 4; ++t) {
      float rsd = za[t] - alpha * va[t];
      pb += rsd * rsd;
    }
    float beta2 = block_sum8(pb, red);
    float beta = sqrtf(fmaxf(beta2, 1e-30f));
    float invb = 1.f / beta;
    if (tid == 0) { al[j] = alpha; b2[j] = beta2; }
#pragma unroll
    for (int t = 0; t < 4; ++t) {
      int i = t * 512 + tid;
      Vprev[i] = (za[t] - alpha * va[t]) * invb;
    }
    float* tmp = Vprev; Vprev = Vcur; Vcur = tmp;
    beta_prev = beta;
    __syncthreads();
  }

  // ---- extreme eigenvalues of T via Sturm bisection (block 0) ----
  if (b == 0) {
    if (tid == 0) {                                  // Gershgorin bounds on T
      float lo = 1e30f, hi = -1e30f;
      for (int i = 1; i <= LK; ++i) {
        float bl = (i > 1) ? sqrtf(b2[i - 1]) : 0.f;
        float br = (i < LK) ? sqrtf(b2[i]) : 0.f;
        lo = fminf(lo, al[i] - bl - br);
        hi = fmaxf(hi, al[i] + bl + br);
      }
      bnds[0] = lo; bnds[1] = hi;
    }
    __syncthreads();
    if (wave < 2) {                 // wave 0 -> lambda_min, wave 1 -> lambda_max
      const int tcount = (wave == 0) ? 1 : LK;
      float lo = bnds[0], hi = bnds[1];
      for (int round = 0; round < 4; ++round) {
        float x = lo + (hi - lo) * (float)(lane + 1) * (1.f / 65.f);
        int cnt = 0;                                 // #eigs of T below x
        float d = al[1] - x;
        if (fabsf(d) < 1e-25f) d = -1e-25f;
        if (d < 0.f) cnt++;
        for (int i = 2; i <= LK; ++i) {
          d = (al[i] - x) - b2[i - 1] / d;
          if (fabsf(d) < 1e-25f) d = -1e-25f;
          if (d < 0.f) cnt++;
        }
        bool ab = (cnt >= tcount);                   // x is above the target eig
        float cand_hi = ab ? x : hi;
        float cand_lo = ab ? lo : x;
#pragma unroll
        for (int off = 32; off; off >>= 1) {
          cand_hi = fminf(cand_hi, __shfl_down(cand_hi, off));
          cand_lo = fmaxf(cand_lo, __shfl_down(cand_lo, off));
        }
        cand_hi = __shfl(cand_hi, 0);
        cand_lo = __shfl(cand_lo, 0);
        hi = cand_hi;
        lo = fminf(cand_lo, hi);
      }
      if (lane == 0) res[wave] = 0.5f * (lo + hi);
    }
    __syncthreads();
    if (tid == 0) {
      float lmin = fmaxf(res[0], 1e-12f);
      float lmax = fmaxf(res[1], 1e-12f);
      out[0] = logf(lmax) - logf(lmin);
    }
  }
}

extern "C" void kernel_launch(void* const* d_in, const int* in_sizes, int n_in,
                              void* d_out, int out_size, void* d_ws, size_t ws_size,
                              hipStream_t stream) {
  const float* pred = (const float*)d_in[0];
  const float* scal = (const float*)d_in[1];
  const float* W    = (const float*)d_in[2];
  const int*   rows = (const int*)d_in[3];
  const int*   cols = (const int*)d_in[4];
  float* out = (float*)d_out;

  // workspace layout (peak ~41.1 MB):
  //  [0,8MB)   : Hf fp16 (dead after gemm) -> Ft fp16
  //  [8,16MB)  : A fp16
  //  [16,24MB) : F fp16
  //  [24,40MB) : M fp32
  //  [40MB,..) : cnt, fixed-stride bins, epoch-tagged Z ping-pong
  char* ws = (char*)d_ws;
  const size_t MB = 1024 * 1024;
  unsigned short* Hf = (unsigned short*)(ws);
  unsigned short* Ah = (unsigned short*)(ws + 8 * MB);
  unsigned short* F  = (unsigned short*)(ws + 16 * MB);
  unsigned short* Ft = (unsigned short*)(ws);          // reuses Hf (dead after gemm)
  float* M = (float*)(ws + 24 * MB);
  char* ctrl = ws + 40 * MB;
  unsigned* cnt  = (unsigned*)(ctrl);                    //  8 KB (zeroed by convert)
  int*      bcol = (int*)(ctrl + 8192);                  //  512 KB (2048 x 64)
  float*    bval = (float*)(ctrl + 8192 + 524288);       //  512 KB
  unsigned long long* Z0 = (unsigned long long*)(ctrl + 8192 + 1048576);         // 16 KB
  unsigned long long* Z1 = (unsigned long long*)(ctrl + 8192 + 1048576 + 16384); // 16 KB

  convert_kernel<<<4096, 256, 0, stream>>>(W, Hf, cnt);
  // symmetric-half double-buffered GEMM (272 tiles) + fused fill
  gemm_f16_kernel<<<272, 512, 0, stream>>>(Hf, Ah, pred, scal, rows, cols, cnt, bcol, bval);

  gatherF_kernel<<<2048, 256, 0, stream>>>(cnt, bcol, bval, Ah, F);    // F = S*A (fp16)
  transpose_kernel<<<dim3(32, 32), 256, 0, stream>>>(F, Ft);           // Ft = F^T
  finalM_kernel<<<2048, 256, 0, stream>>>(cnt, bcol, bval, Ah, F, Ft, M); // M in ONE pass

  // plain launch — 128 blocks x 512 threads, 147KB LDS => 1 block/CU, all resident
  lanczos_kernel<<<NBL, 512, 0, stream>>>(M, Z0, Z1, out);
}